// Round 1
// baseline (565.696 us; speedup 1.0000x reference)
//
#include <hip/hip_runtime.h>
#include <hip/hip_bf16.h>

#define NEG_SLOPE 0.2f

// ---------------- CSR construction ----------------

__global__ void k_hist(const int* __restrict__ dst, int* __restrict__ counts, int E) {
    int e = blockIdx.x * 256 + threadIdx.x;
    if (e < E) atomicAdd(&counts[dst[e]], 1);
}

__global__ __launch_bounds__(1024) void k_scan(const int* __restrict__ counts,
                                               int* __restrict__ row_ptr,
                                               int* __restrict__ row_fill, int N) {
    __shared__ int lds[1024];
    __shared__ int carry_s;
    int tid = threadIdx.x;
    if (tid == 0) carry_s = 0;
    __syncthreads();
    for (int base = 0; base < N; base += 1024) {
        int i = base + tid;
        int v = (i < N) ? counts[i] : 0;
        lds[tid] = v;
        __syncthreads();
        for (int off = 1; off < 1024; off <<= 1) {
            int t = (tid >= off) ? lds[tid - off] : 0;
            __syncthreads();
            lds[tid] += t;
            __syncthreads();
        }
        int incl = lds[tid];
        int excl = incl - v;
        int carry = carry_s;
        if (i < N) { row_ptr[i] = carry + excl; row_fill[i] = carry + excl; }
        __syncthreads();
        if (tid == 1023) carry_s = carry + lds[1023];
        __syncthreads();
    }
    if (tid == 0) row_ptr[N] = carry_s;
}

__global__ void k_scatter(const int* __restrict__ src, const int* __restrict__ dst,
                          int* __restrict__ row_fill, int* __restrict__ esrc, int E) {
    int e = blockIdx.x * 256 + threadIdx.x;
    if (e < E) {
        int p = atomicAdd(&row_fill[dst[e]], 1);
        esrc[p] = src[e];
    }
}

// ---------------- GEMM1: h1 = x @ W1   [M,128]@[128,256] ----------------
// 64x64 tile per block, K=128 fully staged, x tile stored transposed in LDS.

__global__ __launch_bounds__(256) void k_gemm1(const float* __restrict__ x,
                                               const float* __restrict__ W,
                                               float* __restrict__ h, int M) {
    __shared__ float xs[128][64];   // xs[k][m]
    __shared__ float ws[128][64];   // ws[k][c]
    const int tid = threadIdx.x;
    const int row0 = blockIdx.x * 64;
    const int col0 = blockIdx.y * 64;

    // x tile: 64 rows x 128 k -> transposed. lanes vary m (conflict-free LDS writes)
    for (int t = tid; t < 2048; t += 256) {
        int k4 = t >> 6, m = t & 63;
        int r = row0 + m;
        float4 v = make_float4(0.f, 0.f, 0.f, 0.f);
        if (r < M) v = *(const float4*)&x[(size_t)r * 128 + k4 * 4];
        xs[k4 * 4 + 0][m] = v.x;
        xs[k4 * 4 + 1][m] = v.y;
        xs[k4 * 4 + 2][m] = v.z;
        xs[k4 * 4 + 3][m] = v.w;
    }
    // W tile: 128 k x 64 cols
    for (int t = tid; t < 2048; t += 256) {
        int k = t >> 4, c4 = t & 15;
        *(float4*)&ws[k][c4 * 4] = *(const float4*)&W[(size_t)k * 256 + col0 + c4 * 4];
    }
    __syncthreads();

    const int tx = tid & 15, ty = tid >> 4;
    float acc[4][4] = {};
#pragma unroll 4
    for (int k = 0; k < 128; ++k) {
        float4 a = *(const float4*)&xs[k][ty * 4];
        float4 b = *(const float4*)&ws[k][tx * 4];
        float av[4] = {a.x, a.y, a.z, a.w};
        float bv[4] = {b.x, b.y, b.z, b.w};
#pragma unroll
        for (int i = 0; i < 4; ++i)
#pragma unroll
            for (int j = 0; j < 4; ++j) acc[i][j] += av[i] * bv[j];
    }
#pragma unroll
    for (int i = 0; i < 4; ++i) {
        int r = row0 + ty * 4 + i;
        if (r < M)
            *(float4*)&h[(size_t)r * 256 + col0 + tx * 4] =
                make_float4(acc[i][0], acc[i][1], acc[i][2], acc[i][3]);
    }
}

// ---------------- att dots layer 1: a_src/a_dst [N,4] ----------------

__global__ __launch_bounds__(256) void k_att1(const float* __restrict__ h1,
                                              const float* __restrict__ att_src,
                                              const float* __restrict__ att_dst,
                                              float* __restrict__ asrc,
                                              float* __restrict__ adst, int N) {
    int w = threadIdx.x >> 6;
    int lane = threadIdx.x & 63;
    int n = blockIdx.x * 4 + w;
    if (n >= N) return;
#pragma unroll
    for (int hh = 0; hh < 4; ++hh) {
        float hv = h1[(size_t)n * 256 + hh * 64 + lane];
        float s = hv * att_src[hh * 64 + lane];
        float d = hv * att_dst[hh * 64 + lane];
        for (int off = 32; off; off >>= 1) {
            s += __shfl_down(s, off);
            d += __shfl_down(d, off);
        }
        if (lane == 0) { asrc[n * 4 + hh] = s; adst[n * 4 + hh] = d; }
    }
}

// ---------------- agg layer 1: online segment softmax + aggregate + bias + ELU ----------------

__global__ __launch_bounds__(256) void k_agg1(const float* __restrict__ h1,
                                              const float* __restrict__ asrc,
                                              const float* __restrict__ adst,
                                              const int* __restrict__ row_ptr,
                                              const int* __restrict__ esrc,
                                              const float* __restrict__ b1,
                                              float* __restrict__ y1, int N) {
    int n = blockIdx.x;
    int tid = threadIdx.x;
    int hh = tid >> 6;
    float ad = adst[n * 4 + hh];
    int e0 = row_ptr[n], e1 = row_ptr[n + 1];
    float m = -3.0e38f, ssum = 0.f, acc = 0.f;
    for (int e = e0; e < e1; ++e) {
        int s = esrc[e];
        float l = asrc[s * 4 + hh] + ad;
        l = (l >= 0.f) ? l : NEG_SLOPE * l;
        if (l > m) {
            float f = __expf(m - l);
            acc *= f; ssum *= f; m = l;
        }
        float p = __expf(l - m);
        ssum += p;
        acc += p * h1[(size_t)s * 256 + tid];
    }
    float v = acc / (ssum + 1e-16f) + b1[tid];
    y1[(size_t)n * 256 + tid] = (v > 0.f) ? v : (__expf(v) - 1.f);
}

// ---------------- GEMM2: h2 = y1 @ W2   [M,256]@[256,32] ----------------

__global__ __launch_bounds__(256) void k_gemm2(const float* __restrict__ y1,
                                               const float* __restrict__ W,
                                               float* __restrict__ h2, int M) {
    __shared__ float xs[256][32];      // xs[k][m]
    __shared__ float ws2[256 * 32];
    int tid = threadIdx.x;
    int row0 = blockIdx.x * 32;
    for (int t = tid; t < 2048; t += 256) {
        int k4 = t >> 5, m = t & 31;
        int r = row0 + m;
        float4 v = make_float4(0.f, 0.f, 0.f, 0.f);
        if (r < M) v = *(const float4*)&y1[(size_t)r * 256 + k4 * 4];
        xs[k4 * 4 + 0][m] = v.x;
        xs[k4 * 4 + 1][m] = v.y;
        xs[k4 * 4 + 2][m] = v.z;
        xs[k4 * 4 + 3][m] = v.w;
    }
    for (int t = tid; t < 2048; t += 256)
        *(float4*)&ws2[t * 4] = *(const float4*)&W[t * 4];
    __syncthreads();

    int tx = tid & 7, ty = tid >> 3;
    float acc[4] = {};
#pragma unroll 4
    for (int k = 0; k < 256; ++k) {
        float a = xs[k][ty];
        float4 b = *(const float4*)&ws2[k * 32 + tx * 4];
        acc[0] += a * b.x; acc[1] += a * b.y; acc[2] += a * b.z; acc[3] += a * b.w;
    }
    int r = row0 + ty;
    if (r < M)
        *(float4*)&h2[(size_t)r * 32 + tx * 4] = make_float4(acc[0], acc[1], acc[2], acc[3]);
}

// ---------------- att dots layer 2 ----------------

__global__ __launch_bounds__(256) void k_att2(const float* __restrict__ h2,
                                              const float* __restrict__ att_src,
                                              const float* __restrict__ att_dst,
                                              float* __restrict__ asrc,
                                              float* __restrict__ adst, int N) {
    int w = threadIdx.x >> 6;
    int lane = threadIdx.x & 63;
    int n = blockIdx.x * 4 + w;
    if (n >= N) return;
    float s = 0.f, d = 0.f;
    if (lane < 32) {
        float hv = h2[(size_t)n * 32 + lane];
        s = hv * att_src[lane];
        d = hv * att_dst[lane];
    }
    for (int off = 16; off; off >>= 1) {
        s += __shfl_down(s, off);
        d += __shfl_down(d, off);
    }
    if (lane == 0) { asrc[n] = s; adst[n] = d; }
}

// ---------------- agg layer 2: final output ----------------

__global__ __launch_bounds__(256) void k_agg2(const float* __restrict__ h2,
                                              const float* __restrict__ asrc,
                                              const float* __restrict__ adst,
                                              const int* __restrict__ row_ptr,
                                              const int* __restrict__ esrc,
                                              const float* __restrict__ b2,
                                              float* __restrict__ out, int N) {
    int g = threadIdx.x >> 5;
    int c = threadIdx.x & 31;
    int n = blockIdx.x * 8 + g;
    if (n >= N) return;
    float ad = adst[n];
    int e0 = row_ptr[n], e1 = row_ptr[n + 1];
    float m = -3.0e38f, ssum = 0.f, acc = 0.f;
    for (int e = e0; e < e1; ++e) {
        int s = esrc[e];
        float l = asrc[s] + ad;
        l = (l >= 0.f) ? l : NEG_SLOPE * l;
        if (l > m) {
            float f = __expf(m - l);
            acc *= f; ssum *= f; m = l;
        }
        float p = __expf(l - m);
        ssum += p;
        acc += p * h2[(size_t)s * 32 + c];
    }
    out[(size_t)n * 32 + c] = acc / (ssum + 1e-16f) + b2[c];
}

// ---------------- launcher ----------------

extern "C" void kernel_launch(void* const* d_in, const int* in_sizes, int n_in,
                              void* d_out, int out_size, void* d_ws, size_t ws_size,
                              hipStream_t stream) {
    const float* x   = (const float*)d_in[0];
    const int*   ei  = (const int*)d_in[1];
    const float* W1  = (const float*)d_in[2];
    const float* as1 = (const float*)d_in[3];
    const float* ad1 = (const float*)d_in[4];
    const float* b1  = (const float*)d_in[5];
    const float* W2  = (const float*)d_in[6];
    const float* as2 = (const float*)d_in[7];
    const float* ad2 = (const float*)d_in[8];
    const float* b2  = (const float*)d_in[9];
    float* out = (float*)d_out;

    const int N = in_sizes[0] / 128;   // 50000
    const int E = in_sizes[1] / 2;     // 800000
    const int* src = ei;
    const int* dstp = ei + E;

    char* ws = (char*)d_ws;
    size_t off = 0;
    auto alloc = [&](size_t nbytes) {
        void* p = ws + off;
        off += (nbytes + 255) & ~(size_t)255;
        return p;
    };
    int* counts   = (int*)alloc((size_t)N * 4);
    int* row_ptr  = (int*)alloc((size_t)(N + 1) * 4);
    int* row_fill = (int*)alloc((size_t)N * 4);
    int* esrc     = (int*)alloc((size_t)E * 4);
    float* h1     = (float*)alloc((size_t)N * 256 * 4);
    float* y1     = (float*)alloc((size_t)N * 256 * 4);
    float* h2     = (float*)alloc((size_t)N * 32 * 4);
    float* a_s1   = (float*)alloc((size_t)N * 4 * 4);
    float* a_d1   = (float*)alloc((size_t)N * 4 * 4);
    float* a_s2   = (float*)alloc((size_t)N * 4);
    float* a_d2   = (float*)alloc((size_t)N * 4);

    hipMemsetAsync(counts, 0, (size_t)N * 4, stream);
    k_hist<<<(E + 255) / 256, 256, 0, stream>>>(dstp, counts, E);
    k_scan<<<1, 1024, 0, stream>>>(counts, row_ptr, row_fill, N);
    k_scatter<<<(E + 255) / 256, 256, 0, stream>>>(src, dstp, row_fill, esrc, E);

    k_gemm1<<<dim3((N + 63) / 64, 4), 256, 0, stream>>>(x, W1, h1, N);
    k_att1<<<(N + 3) / 4, 256, 0, stream>>>(h1, as1, ad1, a_s1, a_d1, N);
    k_agg1<<<N, 256, 0, stream>>>(h1, a_s1, a_d1, row_ptr, esrc, b1, y1, N);

    k_gemm2<<<(N + 31) / 32, 256, 0, stream>>>(y1, W2, h2, N);
    k_att2<<<(N + 3) / 4, 256, 0, stream>>>(h2, as2, ad2, a_s2, a_d2, N);
    k_agg2<<<(N + 7) / 8, 256, 0, stream>>>(h2, a_s2, a_d2, row_ptr, esrc, b2, out, N);
}

// Round 4
// 476.766 us; speedup vs baseline: 1.1865x; 1.1865x over previous
//
#include <hip/hip_runtime.h>
#include <hip/hip_bf16.h>

#define NEG_SLOPE 0.2f

__device__ __forceinline__ float lrelu(float x) { return x >= 0.f ? x : NEG_SLOPE * x; }

// ---------------- CSR construction ----------------

__global__ void k_hist(const int* __restrict__ dst, int* __restrict__ counts, int E) {
    int e = blockIdx.x * 256 + threadIdx.x;
    if (e < E) atomicAdd(&counts[dst[e]], 1);
}

__global__ __launch_bounds__(1024) void k_scan(const int* __restrict__ counts,
                                               int* __restrict__ row_ptr,
                                               int* __restrict__ row_fill, int N) {
    __shared__ int sums[1024];
    int tid = threadIdx.x;
    int per = (N + 1023) / 1024;
    int start = tid * per;
    int end = min(start + per, N);
    if (start > N) start = N;
    if (end < start) end = start;
    int local = 0;
    for (int i = start; i < end; ++i) local += counts[i];
    sums[tid] = local;
    __syncthreads();
    for (int off = 1; off < 1024; off <<= 1) {
        int t = (tid >= off) ? sums[tid - off] : 0;
        __syncthreads();
        sums[tid] += t;
        __syncthreads();
    }
    int run = sums[tid] - local;  // exclusive prefix
    for (int i = start; i < end; ++i) {
        row_ptr[i] = run;
        row_fill[i] = run;
        run += counts[i];
    }
    if (tid == 1023) row_ptr[N] = run;
}

__global__ void k_scatter(const int* __restrict__ src, const int* __restrict__ dst,
                          int* __restrict__ row_fill, int* __restrict__ esrc, int E) {
    int e = blockIdx.x * 256 + threadIdx.x;
    if (e < E) {
        int p = atomicAdd(&row_fill[dst[e]], 1);
        esrc[p] = src[e];
    }
}

// ---------------- GEMM1: h1 = x @ W1  [M,128]@[128,256], fused att dots ----------------

__global__ __launch_bounds__(256) void k_gemm1(const float* __restrict__ x,
                                               const float* __restrict__ W,
                                               const float* __restrict__ att_src,
                                               const float* __restrict__ att_dst,
                                               float* __restrict__ h,
                                               float* __restrict__ a_s,
                                               float* __restrict__ a_d, int M) {
    __shared__ float xs[128][64];   // xs[k][m]
    __shared__ float ws[128][64];   // ws[k][c]
    const int tid = threadIdx.x;
    const int row0 = blockIdx.x * 64;
    const int hh = blockIdx.y;           // head == 64-col tile
    const int col0 = hh * 64;

    for (int t = tid; t < 2048; t += 256) {
        int k4 = t >> 6, m = t & 63;
        int r = row0 + m;
        float4 v = make_float4(0.f, 0.f, 0.f, 0.f);
        if (r < M) v = *(const float4*)&x[(size_t)r * 128 + k4 * 4];
        xs[k4 * 4 + 0][m] = v.x;
        xs[k4 * 4 + 1][m] = v.y;
        xs[k4 * 4 + 2][m] = v.z;
        xs[k4 * 4 + 3][m] = v.w;
    }
    for (int t = tid; t < 2048; t += 256) {
        int k = t >> 4, c4 = t & 15;
        *(float4*)&ws[k][c4 * 4] = *(const float4*)&W[(size_t)k * 256 + col0 + c4 * 4];
    }
    __syncthreads();

    const int tx = tid & 15, ty = tid >> 4;
    float acc[4][4] = {};
#pragma unroll 4
    for (int k = 0; k < 128; ++k) {
        float4 a = *(const float4*)&xs[k][ty * 4];
        float4 b = *(const float4*)&ws[k][tx * 4];
        float av[4] = {a.x, a.y, a.z, a.w};
        float bv[4] = {b.x, b.y, b.z, b.w};
#pragma unroll
        for (int i = 0; i < 4; ++i)
#pragma unroll
            for (int j = 0; j < 4; ++j) acc[i][j] += av[i] * bv[j];
    }

    float asv[4], adv[4];
#pragma unroll
    for (int j = 0; j < 4; ++j) {
        asv[j] = att_src[col0 + tx * 4 + j];
        adv[j] = att_dst[col0 + tx * 4 + j];
    }
#pragma unroll
    for (int i = 0; i < 4; ++i) {
        int r = row0 + ty * 4 + i;
        if (r < M)
            *(float4*)&h[(size_t)r * 256 + col0 + tx * 4] =
                make_float4(acc[i][0], acc[i][1], acc[i][2], acc[i][3]);
        float s_ = 0.f, d_ = 0.f;
#pragma unroll
        for (int j = 0; j < 4; ++j) {
            s_ = fmaf(acc[i][j], asv[j], s_);
            d_ = fmaf(acc[i][j], adv[j], d_);
        }
#pragma unroll
        for (int off = 1; off < 16; off <<= 1) {
            s_ += __shfl_xor(s_, off);
            d_ += __shfl_xor(d_, off);
        }
        if (tx == 0 && r < M) {
            a_s[(size_t)r * 4 + hh] = s_;
            a_d[(size_t)r * 4 + hh] = d_;
        }
    }
}

// ---------------- alpha layer 1: p = exp(l - max) per edge, CSR order ----------------

__global__ __launch_bounds__(256) void k_alpha1(const float* __restrict__ asrc,
                                                const float* __restrict__ adst,
                                                const int* __restrict__ row_ptr,
                                                const int* __restrict__ esrc,
                                                float* __restrict__ alpha, int N) {
    int wv = threadIdx.x >> 6, lane = threadIdx.x & 63;
    int n = blockIdx.x * 4 + wv;
    if (n >= N) return;
    int e0 = row_ptr[n], e1 = row_ptr[n + 1];
    int deg = e1 - e0;
    if (deg == 0) return;
    const float4 ad = *(const float4*)&adst[(size_t)n * 4];
    if (deg <= 64) {
        float4 l = make_float4(-3e38f, -3e38f, -3e38f, -3e38f);
        if (lane < deg) {
            int s = esrc[e0 + lane];
            float4 as = *(const float4*)&asrc[(size_t)s * 4];
            l.x = lrelu(as.x + ad.x); l.y = lrelu(as.y + ad.y);
            l.z = lrelu(as.z + ad.z); l.w = lrelu(as.w + ad.w);
        }
        float4 m = l;
#pragma unroll
        for (int off = 32; off; off >>= 1) {
            m.x = fmaxf(m.x, __shfl_xor(m.x, off));
            m.y = fmaxf(m.y, __shfl_xor(m.y, off));
            m.z = fmaxf(m.z, __shfl_xor(m.z, off));
            m.w = fmaxf(m.w, __shfl_xor(m.w, off));
        }
        if (lane < deg) {
            float4 p;
            p.x = __expf(l.x - m.x); p.y = __expf(l.y - m.y);
            p.z = __expf(l.z - m.z); p.w = __expf(l.w - m.w);
            *(float4*)&alpha[(size_t)(e0 + lane) * 4] = p;
        }
    } else {
        float4 m = make_float4(-3e38f, -3e38f, -3e38f, -3e38f);
        for (int p0 = e0; p0 < e1; p0 += 64) {
            int e = p0 + lane;
            if (e < e1) {
                int s = esrc[e];
                float4 as = *(const float4*)&asrc[(size_t)s * 4];
                m.x = fmaxf(m.x, lrelu(as.x + ad.x));
                m.y = fmaxf(m.y, lrelu(as.y + ad.y));
                m.z = fmaxf(m.z, lrelu(as.z + ad.z));
                m.w = fmaxf(m.w, lrelu(as.w + ad.w));
            }
        }
#pragma unroll
        for (int off = 32; off; off >>= 1) {
            m.x = fmaxf(m.x, __shfl_xor(m.x, off));
            m.y = fmaxf(m.y, __shfl_xor(m.y, off));
            m.z = fmaxf(m.z, __shfl_xor(m.z, off));
            m.w = fmaxf(m.w, __shfl_xor(m.w, off));
        }
        for (int p0 = e0; p0 < e1; p0 += 64) {
            int e = p0 + lane;
            if (e < e1) {
                int s = esrc[e];
                float4 as = *(const float4*)&asrc[(size_t)s * 4];
                float4 p;
                p.x = __expf(lrelu(as.x + ad.x) - m.x);
                p.y = __expf(lrelu(as.y + ad.y) - m.y);
                p.z = __expf(lrelu(as.z + ad.z) - m.z);
                p.w = __expf(lrelu(as.w + ad.w) - m.w);
                *(float4*)&alpha[(size_t)e * 4] = p;
            }
        }
    }
}

// ---------------- agg layer 1: weighted gather + bias + ELU ----------------

__global__ __launch_bounds__(256) void k_agg1(const float* __restrict__ h1,
                                              const int* __restrict__ row_ptr,
                                              const int* __restrict__ esrc,
                                              const float* __restrict__ alpha,
                                              const float* __restrict__ b1,
                                              float* __restrict__ y1, int N) {
    __shared__ int ss[64];
    __shared__ float sa[256];
    int n = blockIdx.x;
    int tid = threadIdx.x;
    int hh = tid >> 6;
    int e0 = row_ptr[n], e1 = row_ptr[n + 1];
    float acc = 0.f, ssum = 0.f;
    for (int p0 = e0; p0 < e1; p0 += 64) {
        int cnt = min(64, e1 - p0);
        __syncthreads();
        if (tid < cnt) ss[tid] = esrc[p0 + tid];
        int i2 = tid - 64;
        if (i2 >= 0 && i2 < cnt)
            *(float4*)&sa[i2 * 4] = *(const float4*)&alpha[(size_t)(p0 + i2) * 4];
        __syncthreads();
        int i = 0;
        for (; i + 1 < cnt; i += 2) {
            int s0 = ss[i], s1 = ss[i + 1];
            float a0 = sa[i * 4 + hh], a1 = sa[(i + 1) * 4 + hh];
            float v0 = h1[(size_t)s0 * 256 + tid];
            float v1 = h1[(size_t)s1 * 256 + tid];
            acc = fmaf(a0, v0, acc);
            acc = fmaf(a1, v1, acc);
            ssum += a0 + a1;
        }
        if (i < cnt) {
            int s0 = ss[i];
            float a0 = sa[i * 4 + hh];
            acc = fmaf(a0, h1[(size_t)s0 * 256 + tid], acc);
            ssum += a0;
        }
    }
    float v = acc / (ssum + 1e-16f) + b1[tid];
    y1[(size_t)n * 256 + tid] = (v > 0.f) ? v : (__expf(v) - 1.f);
}

// ---------------- GEMM2: h2 = y1 @ W2  [M,256]@[256,32], fused att dots ----------------

__global__ __launch_bounds__(256) void k_gemm2(const float* __restrict__ y1,
                                               const float* __restrict__ W,
                                               const float* __restrict__ att_src,
                                               const float* __restrict__ att_dst,
                                               float* __restrict__ h2,
                                               float* __restrict__ a_s,
                                               float* __restrict__ a_d, int M) {
    __shared__ float xs[256][32];
    __shared__ float ws2[256 * 32];
    int tid = threadIdx.x;
    int row0 = blockIdx.x * 32;
    for (int t = tid; t < 2048; t += 256) {
        int k4 = t >> 5, m = t & 31;
        int r = row0 + m;
        float4 v = make_float4(0.f, 0.f, 0.f, 0.f);
        if (r < M) v = *(const float4*)&y1[(size_t)r * 256 + k4 * 4];
        xs[k4 * 4 + 0][m] = v.x;
        xs[k4 * 4 + 1][m] = v.y;
        xs[k4 * 4 + 2][m] = v.z;
        xs[k4 * 4 + 3][m] = v.w;
    }
    for (int t = tid; t < 2048; t += 256)
        *(float4*)&ws2[t * 4] = *(const float4*)&W[t * 4];
    __syncthreads();

    int tx = tid & 7, ty = tid >> 3;
    float acc[4] = {};
#pragma unroll 4
    for (int k = 0; k < 256; ++k) {
        float a = xs[k][ty];
        float4 b = *(const float4*)&ws2[k * 32 + tx * 4];
        acc[0] += a * b.x; acc[1] += a * b.y; acc[2] += a * b.z; acc[3] += a * b.w;
    }
    int r = row0 + ty;
    if (r < M)
        *(float4*)&h2[(size_t)r * 32 + tx * 4] = make_float4(acc[0], acc[1], acc[2], acc[3]);

    float s_ = 0.f, d_ = 0.f;
#pragma unroll
    for (int j = 0; j < 4; ++j) {
        s_ = fmaf(acc[j], att_src[tx * 4 + j], s_);
        d_ = fmaf(acc[j], att_dst[tx * 4 + j], d_);
    }
#pragma unroll
    for (int off = 1; off < 8; off <<= 1) {
        s_ += __shfl_xor(s_, off);
        d_ += __shfl_xor(d_, off);
    }
    if (tx == 0 && r < M) { a_s[r] = s_; a_d[r] = d_; }
}

// ---------------- alpha layer 2 ----------------

__global__ __launch_bounds__(256) void k_alpha2(const float* __restrict__ asrc,
                                                const float* __restrict__ adst,
                                                const int* __restrict__ row_ptr,
                                                const int* __restrict__ esrc,
                                                float* __restrict__ alpha, int N) {
    int g = threadIdx.x >> 5, c = threadIdx.x & 31;
    int n = blockIdx.x * 8 + g;
    if (n >= N) return;
    int e0 = row_ptr[n], e1 = row_ptr[n + 1];
    int deg = e1 - e0;
    if (deg == 0) return;
    float ad = adst[n];
    if (deg <= 32) {
        float l = -3e38f;
        if (c < deg) l = lrelu(asrc[esrc[e0 + c]] + ad);
        float m = l;
#pragma unroll
        for (int off = 16; off; off >>= 1) m = fmaxf(m, __shfl_xor(m, off));
        if (c < deg) alpha[e0 + c] = __expf(l - m);
    } else {
        float m = -3e38f;
        for (int p0 = e0; p0 < e1; p0 += 32) {
            int e = p0 + c;
            if (e < e1) m = fmaxf(m, lrelu(asrc[esrc[e]] + ad));
        }
#pragma unroll
        for (int off = 16; off; off >>= 1) m = fmaxf(m, __shfl_xor(m, off));
        for (int p0 = e0; p0 < e1; p0 += 32) {
            int e = p0 + c;
            if (e < e1) alpha[e] = __expf(lrelu(asrc[esrc[e]] + ad) - m);
        }
    }
}

// ---------------- agg layer 2: final output ----------------

__global__ __launch_bounds__(256) void k_agg2(const float* __restrict__ h2,
                                              const int* __restrict__ row_ptr,
                                              const int* __restrict__ esrc,
                                              const float* __restrict__ alpha,
                                              const float* __restrict__ b2,
                                              float* __restrict__ out, int N) {
    __shared__ int ss[8][32];
    __shared__ float sa[8][32];
    __shared__ int degs[8];
    int tid = threadIdx.x;
    int g = tid >> 5, c = tid & 31;
    int n = blockIdx.x * 8 + g;
    if (tid < 8) {
        int nn = blockIdx.x * 8 + tid;
        degs[tid] = (nn < N) ? row_ptr[nn + 1] - row_ptr[nn] : 0;
    }
    __syncthreads();
    int maxdeg = 0;
#pragma unroll
    for (int k = 0; k < 8; ++k) maxdeg = max(maxdeg, degs[k]);
    int e0 = 0, e1 = 0;
    if (n < N) { e0 = row_ptr[n]; e1 = row_ptr[n + 1]; }
    float acc = 0.f, ssum = 0.f;
    int nchunk = (maxdeg + 31) >> 5;
    for (int ci = 0; ci < nchunk; ++ci) {
        int p0 = e0 + ci * 32;
        int cnt = min(32, e1 - p0);
        if (cnt < 0) cnt = 0;
        __syncthreads();
        if (c < cnt) {
            ss[g][c] = esrc[p0 + c];
            sa[g][c] = alpha[p0 + c];
        }
        __syncthreads();
        int i = 0;
        for (; i + 1 < cnt; i += 2) {
            int s0 = ss[g][i], s1 = ss[g][i + 1];
            float a0 = sa[g][i], a1 = sa[g][i + 1];
            float v0 = h2[(size_t)s0 * 32 + c];
            float v1 = h2[(size_t)s1 * 32 + c];
            acc = fmaf(a0, v0, acc);
            acc = fmaf(a1, v1, acc);
            ssum += a0 + a1;
        }
        if (i < cnt) {
            int s0 = ss[g][i];
            float a0 = sa[g][i];
            acc = fmaf(a0, h2[(size_t)s0 * 32 + c], acc);
            ssum += a0;
        }
    }
    if (n < N) out[(size_t)n * 32 + c] = acc / (ssum + 1e-16f) + b2[c];
}

// ---------------- launcher ----------------

extern "C" void kernel_launch(void* const* d_in, const int* in_sizes, int n_in,
                              void* d_out, int out_size, void* d_ws, size_t ws_size,
                              hipStream_t stream) {
    const float* x   = (const float*)d_in[0];
    const int*   ei  = (const int*)d_in[1];
    const float* W1  = (const float*)d_in[2];
    const float* as1 = (const float*)d_in[3];
    const float* ad1 = (const float*)d_in[4];
    const float* b1  = (const float*)d_in[5];
    const float* W2  = (const float*)d_in[6];
    const float* as2 = (const float*)d_in[7];
    const float* ad2 = (const float*)d_in[8];
    const float* b2  = (const float*)d_in[9];
    float* out = (float*)d_out;

    const int N = in_sizes[0] / 128;   // 50000
    const int E = in_sizes[1] / 2;     // 800000
    const int* src = ei;
    const int* dstp = ei + E;

    char* ws = (char*)d_ws;
    size_t off = 0;
    auto alloc = [&](size_t nbytes) {
        void* p = ws + off;
        off += (nbytes + 255) & ~(size_t)255;
        return p;
    };
    int* counts    = (int*)alloc((size_t)N * 4);
    int* row_ptr   = (int*)alloc((size_t)(N + 1) * 4);
    int* row_fill  = (int*)alloc((size_t)N * 4);
    int* esrc      = (int*)alloc((size_t)E * 4);
    float* h1      = (float*)alloc((size_t)N * 256 * 4);
    float* y1      = (float*)alloc((size_t)N * 256 * 4);
    float* h2      = (float*)alloc((size_t)N * 32 * 4);
    float* a_s1    = (float*)alloc((size_t)N * 4 * 4);
    float* a_d1    = (float*)alloc((size_t)N * 4 * 4);
    float* a_s2    = (float*)alloc((size_t)N * 4);
    float* a_d2    = (float*)alloc((size_t)N * 4);
    float* alpha1  = (float*)alloc((size_t)E * 4 * 4);
    float* alpha2  = (float*)alloc((size_t)E * 4);

    hipMemsetAsync(counts, 0, (size_t)N * 4, stream);
    k_hist<<<(E + 255) / 256, 256, 0, stream>>>(dstp, counts, E);
    k_scan<<<1, 1024, 0, stream>>>(counts, row_ptr, row_fill, N);
    k_scatter<<<(E + 255) / 256, 256, 0, stream>>>(src, dstp, row_fill, esrc, E);

    k_gemm1<<<dim3((N + 63) / 64, 4), 256, 0, stream>>>(x, W1, as1, ad1, h1, a_s1, a_d1, N);
    k_alpha1<<<(N + 3) / 4, 256, 0, stream>>>(a_s1, a_d1, row_ptr, esrc, alpha1, N);
    k_agg1<<<N, 256, 0, stream>>>(h1, row_ptr, esrc, alpha1, b1, y1, N);

    k_gemm2<<<(N + 31) / 32, 256, 0, stream>>>(y1, W2, as2, ad2, h2, a_s2, a_d2, N);
    k_alpha2<<<(N + 7) / 8, 256, 0, stream>>>(a_s2, a_d2, row_ptr, esrc, alpha2, N);
    k_agg2<<<(N + 7) / 8, 256, 0, stream>>>(h2, row_ptr, esrc, alpha2, b2, out, N);
}

// Round 5
// 371.220 us; speedup vs baseline: 1.5239x; 1.2843x over previous
//
#include <hip/hip_runtime.h>
#include <hip/hip_bf16.h>

#define NEG_SLOPE 0.2f

__device__ __forceinline__ float lrelu(float x) { return x >= 0.f ? x : NEG_SLOPE * x; }

// ---------------- CSR construction ----------------

__global__ void k_hist(const int* __restrict__ dst, int* __restrict__ counts, int E) {
    int e = blockIdx.x * 256 + threadIdx.x;
    if (e < E) atomicAdd(&counts[dst[e]], 1);
}

// 3-level parallel scan: per-block sums -> scan sums -> per-block rescan
__global__ __launch_bounds__(256) void k_scan1(const int* __restrict__ counts,
                                               int* __restrict__ bsum, int N) {
    __shared__ int wsum[4];
    int b = blockIdx.x, t = threadIdx.x;
    int i0 = b * 1024 + t * 4;
    int s = 0;
    if (i0 < N) { int4 v = *(const int4*)&counts[i0]; s = v.x + v.y + v.z + v.w; }
#pragma unroll
    for (int off = 32; off; off >>= 1) s += __shfl_down(s, off);
    if ((t & 63) == 0) wsum[t >> 6] = s;
    __syncthreads();
    if (t == 0) bsum[b] = wsum[0] + wsum[1] + wsum[2] + wsum[3];
}

__global__ void k_scan2(const int* __restrict__ bsum, int* __restrict__ boff,
                        int* __restrict__ row_ptrN, int nb) {
    int t = threadIdx.x;  // 64 threads, nb <= 64
    int v = (t < nb) ? bsum[t] : 0;
    int incl = v;
#pragma unroll
    for (int off = 1; off < 64; off <<= 1) {
        int u = __shfl_up(incl, off);
        if (t >= off) incl += u;
    }
    if (t < nb) boff[t] = incl - v;
    if (t == nb - 1) *row_ptrN = incl;
}

__global__ __launch_bounds__(256) void k_scan3(const int* __restrict__ counts,
                                               const int* __restrict__ boff,
                                               int* __restrict__ row_ptr,
                                               int* __restrict__ row_fill, int N) {
    __shared__ int lds[256];
    int b = blockIdx.x, t = threadIdx.x;
    int i0 = b * 1024 + t * 4;
    int4 v = make_int4(0, 0, 0, 0);
    if (i0 < N) v = *(const int4*)&counts[i0];
    int tot = v.x + v.y + v.z + v.w;
    lds[t] = tot;
    __syncthreads();
    for (int off = 1; off < 256; off <<= 1) {
        int u = (t >= off) ? lds[t - off] : 0;
        __syncthreads();
        lds[t] += u;
        __syncthreads();
    }
    int excl = lds[t] - tot;
    int run = boff[b] + excl;
    if (i0 < N) {
        row_ptr[i0] = run;     row_fill[i0] = run;     run += v.x;
        row_ptr[i0 + 1] = run; row_fill[i0 + 1] = run; run += v.y;
        row_ptr[i0 + 2] = run; row_fill[i0 + 2] = run; run += v.z;
        row_ptr[i0 + 3] = run; row_fill[i0 + 3] = run;
    }
}

__global__ void k_scatter(const int* __restrict__ src, const int* __restrict__ dst,
                          int* __restrict__ row_fill, int* __restrict__ esrc, int E) {
    int e = blockIdx.x * 256 + threadIdx.x;
    if (e < E) {
        int p = atomicAdd(&row_fill[dst[e]], 1);
        esrc[p] = src[e];
    }
}

// ---------------- GEMM1: h1 = x @ W1  [M,128]@[128,256], fused att dots ----------------

__global__ __launch_bounds__(256) void k_gemm1(const float* __restrict__ x,
                                               const float* __restrict__ W,
                                               const float* __restrict__ att_src,
                                               const float* __restrict__ att_dst,
                                               float* __restrict__ h,
                                               float* __restrict__ a_s,
                                               float* __restrict__ a_d, int M) {
    __shared__ float xs[128][64];   // xs[k][m]
    __shared__ float ws[128][64];   // ws[k][c]
    const int tid = threadIdx.x;
    const int row0 = blockIdx.x * 64;
    const int hh = blockIdx.y;           // head == 64-col tile
    const int col0 = hh * 64;

    for (int t = tid; t < 2048; t += 256) {
        int k4 = t >> 6, m = t & 63;
        int r = row0 + m;
        float4 v = make_float4(0.f, 0.f, 0.f, 0.f);
        if (r < M) v = *(const float4*)&x[(size_t)r * 128 + k4 * 4];
        xs[k4 * 4 + 0][m] = v.x;
        xs[k4 * 4 + 1][m] = v.y;
        xs[k4 * 4 + 2][m] = v.z;
        xs[k4 * 4 + 3][m] = v.w;
    }
    for (int t = tid; t < 2048; t += 256) {
        int k = t >> 4, c4 = t & 15;
        *(float4*)&ws[k][c4 * 4] = *(const float4*)&W[(size_t)k * 256 + col0 + c4 * 4];
    }
    __syncthreads();

    const int tx = tid & 15, ty = tid >> 4;
    float acc[4][4] = {};
#pragma unroll 4
    for (int k = 0; k < 128; ++k) {
        float4 a = *(const float4*)&xs[k][ty * 4];
        float4 b = *(const float4*)&ws[k][tx * 4];
        float av[4] = {a.x, a.y, a.z, a.w};
        float bv[4] = {b.x, b.y, b.z, b.w};
#pragma unroll
        for (int i = 0; i < 4; ++i)
#pragma unroll
            for (int j = 0; j < 4; ++j) acc[i][j] += av[i] * bv[j];
    }

    float asv[4], adv[4];
#pragma unroll
    for (int j = 0; j < 4; ++j) {
        asv[j] = att_src[col0 + tx * 4 + j];
        adv[j] = att_dst[col0 + tx * 4 + j];
    }
#pragma unroll
    for (int i = 0; i < 4; ++i) {
        int r = row0 + ty * 4 + i;
        if (r < M)
            *(float4*)&h[(size_t)r * 256 + col0 + tx * 4] =
                make_float4(acc[i][0], acc[i][1], acc[i][2], acc[i][3]);
        float s_ = 0.f, d_ = 0.f;
#pragma unroll
        for (int j = 0; j < 4; ++j) {
            s_ = fmaf(acc[i][j], asv[j], s_);
            d_ = fmaf(acc[i][j], adv[j], d_);
        }
#pragma unroll
        for (int off = 1; off < 16; off <<= 1) {
            s_ += __shfl_xor(s_, off);
            d_ += __shfl_xor(d_, off);
        }
        if (tx == 0 && r < M) {
            a_s[(size_t)r * 4 + hh] = s_;
            a_d[(size_t)r * 4 + hh] = d_;
        }
    }
}

// ---------------- alpha layer 1: p = exp(l - max) per edge, CSR order ----------------

__global__ __launch_bounds__(256) void k_alpha1(const float* __restrict__ asrc,
                                                const float* __restrict__ adst,
                                                const int* __restrict__ row_ptr,
                                                const int* __restrict__ esrc,
                                                float* __restrict__ alpha, int N) {
    int wv = threadIdx.x >> 6, lane = threadIdx.x & 63;
    int n = blockIdx.x * 4 + wv;
    if (n >= N) return;
    int e0 = row_ptr[n], e1 = row_ptr[n + 1];
    int deg = e1 - e0;
    if (deg == 0) return;
    const float4 ad = *(const float4*)&adst[(size_t)n * 4];
    if (deg <= 64) {
        float4 l = make_float4(-3e38f, -3e38f, -3e38f, -3e38f);
        if (lane < deg) {
            int s = esrc[e0 + lane];
            float4 as = *(const float4*)&asrc[(size_t)s * 4];
            l.x = lrelu(as.x + ad.x); l.y = lrelu(as.y + ad.y);
            l.z = lrelu(as.z + ad.z); l.w = lrelu(as.w + ad.w);
        }
        float4 m = l;
#pragma unroll
        for (int off = 32; off; off >>= 1) {
            m.x = fmaxf(m.x, __shfl_xor(m.x, off));
            m.y = fmaxf(m.y, __shfl_xor(m.y, off));
            m.z = fmaxf(m.z, __shfl_xor(m.z, off));
            m.w = fmaxf(m.w, __shfl_xor(m.w, off));
        }
        if (lane < deg) {
            float4 p;
            p.x = __expf(l.x - m.x); p.y = __expf(l.y - m.y);
            p.z = __expf(l.z - m.z); p.w = __expf(l.w - m.w);
            *(float4*)&alpha[(size_t)(e0 + lane) * 4] = p;
        }
    } else {
        float4 m = make_float4(-3e38f, -3e38f, -3e38f, -3e38f);
        for (int p0 = e0; p0 < e1; p0 += 64) {
            int e = p0 + lane;
            if (e < e1) {
                int s = esrc[e];
                float4 as = *(const float4*)&asrc[(size_t)s * 4];
                m.x = fmaxf(m.x, lrelu(as.x + ad.x));
                m.y = fmaxf(m.y, lrelu(as.y + ad.y));
                m.z = fmaxf(m.z, lrelu(as.z + ad.z));
                m.w = fmaxf(m.w, lrelu(as.w + ad.w));
            }
        }
#pragma unroll
        for (int off = 32; off; off >>= 1) {
            m.x = fmaxf(m.x, __shfl_xor(m.x, off));
            m.y = fmaxf(m.y, __shfl_xor(m.y, off));
            m.z = fmaxf(m.z, __shfl_xor(m.z, off));
            m.w = fmaxf(m.w, __shfl_xor(m.w, off));
        }
        for (int p0 = e0; p0 < e1; p0 += 64) {
            int e = p0 + lane;
            if (e < e1) {
                int s = esrc[e];
                float4 as = *(const float4*)&asrc[(size_t)s * 4];
                float4 p;
                p.x = __expf(lrelu(as.x + ad.x) - m.x);
                p.y = __expf(lrelu(as.y + ad.y) - m.y);
                p.z = __expf(lrelu(as.z + ad.z) - m.z);
                p.w = __expf(lrelu(as.w + ad.w) - m.w);
                *(float4*)&alpha[(size_t)e * 4] = p;
            }
        }
    }
}

// ---------------- agg layer 1: wave-per-node, barrier-free, float4 lanes ----------------

__global__ __launch_bounds__(256) void k_agg1(const float* __restrict__ h1,
                                              const int* __restrict__ row_ptr,
                                              const int* __restrict__ esrc,
                                              const float* __restrict__ alpha,
                                              const float* __restrict__ b1,
                                              float* __restrict__ y1, int N) {
    __shared__ int ss[4][64];
    __shared__ float sa[4][64 * 4];
    int tid = threadIdx.x;
    int wv = tid >> 6, lane = tid & 63;
    int n = blockIdx.x * 4 + wv;
    if (n >= N) return;
    int head = lane >> 4;                 // channels lane*4..lane*4+3 are all in head lane/16
    int e0 = row_ptr[n], e1 = row_ptr[n + 1];
    float4 acc = make_float4(0.f, 0.f, 0.f, 0.f);
    float4 asum = make_float4(0.f, 0.f, 0.f, 0.f);

    for (int p0 = e0; p0 < e1; p0 += 64) {
        int cnt = min(64, e1 - p0);
        if (lane < cnt) {
            ss[wv][lane] = esrc[p0 + lane];
            float4 a4 = *(const float4*)&alpha[(size_t)(p0 + lane) * 4];
            *(float4*)&sa[wv][lane * 4] = a4;
            asum.x += a4.x; asum.y += a4.y; asum.z += a4.z; asum.w += a4.w;
        }
        // same-wave LDS write->read is in program order on CDNA: no barrier needed
        int i = 0;
        for (; i + 1 < cnt; i += 2) {
            int s0 = ss[wv][i], s1 = ss[wv][i + 1];
            float a0 = sa[wv][i * 4 + head], a1 = sa[wv][(i + 1) * 4 + head];
            float4 v0 = *(const float4*)&h1[(size_t)s0 * 256 + lane * 4];
            float4 v1 = *(const float4*)&h1[(size_t)s1 * 256 + lane * 4];
            acc.x = fmaf(a0, v0.x, acc.x); acc.y = fmaf(a0, v0.y, acc.y);
            acc.z = fmaf(a0, v0.z, acc.z); acc.w = fmaf(a0, v0.w, acc.w);
            acc.x = fmaf(a1, v1.x, acc.x); acc.y = fmaf(a1, v1.y, acc.y);
            acc.z = fmaf(a1, v1.z, acc.z); acc.w = fmaf(a1, v1.w, acc.w);
        }
        if (i < cnt) {
            int s0 = ss[wv][i];
            float a0 = sa[wv][i * 4 + head];
            float4 v0 = *(const float4*)&h1[(size_t)s0 * 256 + lane * 4];
            acc.x = fmaf(a0, v0.x, acc.x); acc.y = fmaf(a0, v0.y, acc.y);
            acc.z = fmaf(a0, v0.z, acc.z); acc.w = fmaf(a0, v0.w, acc.w);
        }
    }

    // wave-reduce staged alpha sums -> per-head denominators
#pragma unroll
    for (int off = 1; off < 64; off <<= 1) {
        asum.x += __shfl_xor(asum.x, off);
        asum.y += __shfl_xor(asum.y, off);
        asum.z += __shfl_xor(asum.z, off);
        asum.w += __shfl_xor(asum.w, off);
    }
    float ssum = (head == 0) ? asum.x : (head == 1) ? asum.y : (head == 2) ? asum.z : asum.w;
    float inv = 1.f / (ssum + 1e-16f);
    float4 bb = *(const float4*)&b1[lane * 4];
    float4 v;
    v.x = acc.x * inv + bb.x; v.y = acc.y * inv + bb.y;
    v.z = acc.z * inv + bb.z; v.w = acc.w * inv + bb.w;
    v.x = (v.x > 0.f) ? v.x : (__expf(v.x) - 1.f);
    v.y = (v.y > 0.f) ? v.y : (__expf(v.y) - 1.f);
    v.z = (v.z > 0.f) ? v.z : (__expf(v.z) - 1.f);
    v.w = (v.w > 0.f) ? v.w : (__expf(v.w) - 1.f);
    *(float4*)&y1[(size_t)n * 256 + lane * 4] = v;
}

// ---------------- GEMM2: h2 = y1 @ W2  [M,256]@[256,32], fused att dots ----------------

__global__ __launch_bounds__(256) void k_gemm2(const float* __restrict__ y1,
                                               const float* __restrict__ W,
                                               const float* __restrict__ att_src,
                                               const float* __restrict__ att_dst,
                                               float* __restrict__ h2,
                                               float* __restrict__ a_s,
                                               float* __restrict__ a_d, int M) {
    __shared__ float xs[256][32];
    __shared__ float ws2[256 * 32];
    int tid = threadIdx.x;
    int row0 = blockIdx.x * 32;
    for (int t = tid; t < 2048; t += 256) {
        int k4 = t >> 5, m = t & 31;
        int r = row0 + m;
        float4 v = make_float4(0.f, 0.f, 0.f, 0.f);
        if (r < M) v = *(const float4*)&y1[(size_t)r * 256 + k4 * 4];
        xs[k4 * 4 + 0][m] = v.x;
        xs[k4 * 4 + 1][m] = v.y;
        xs[k4 * 4 + 2][m] = v.z;
        xs[k4 * 4 + 3][m] = v.w;
    }
    for (int t = tid; t < 2048; t += 256)
        *(float4*)&ws2[t * 4] = *(const float4*)&W[t * 4];
    __syncthreads();

    int tx = tid & 7, ty = tid >> 3;
    float acc[4] = {};
#pragma unroll 4
    for (int k = 0; k < 256; ++k) {
        float a = xs[k][ty];
        float4 b = *(const float4*)&ws2[k * 32 + tx * 4];
        acc[0] += a * b.x; acc[1] += a * b.y; acc[2] += a * b.z; acc[3] += a * b.w;
    }
    int r = row0 + ty;
    if (r < M)
        *(float4*)&h2[(size_t)r * 32 + tx * 4] = make_float4(acc[0], acc[1], acc[2], acc[3]);

    float s_ = 0.f, d_ = 0.f;
#pragma unroll
    for (int j = 0; j < 4; ++j) {
        s_ = fmaf(acc[j], att_src[tx * 4 + j], s_);
        d_ = fmaf(acc[j], att_dst[tx * 4 + j], d_);
    }
#pragma unroll
    for (int off = 1; off < 8; off <<= 1) {
        s_ += __shfl_xor(s_, off);
        d_ += __shfl_xor(d_, off);
    }
    if (tx == 0 && r < M) { a_s[r] = s_; a_d[r] = d_; }
}

// ---------------- alpha layer 2 ----------------

__global__ __launch_bounds__(256) void k_alpha2(const float* __restrict__ asrc,
                                                const float* __restrict__ adst,
                                                const int* __restrict__ row_ptr,
                                                const int* __restrict__ esrc,
                                                float* __restrict__ alpha, int N) {
    int g = threadIdx.x >> 5, c = threadIdx.x & 31;
    int n = blockIdx.x * 8 + g;
    if (n >= N) return;
    int e0 = row_ptr[n], e1 = row_ptr[n + 1];
    int deg = e1 - e0;
    if (deg == 0) return;
    float ad = adst[n];
    if (deg <= 32) {
        float l = -3e38f;
        if (c < deg) l = lrelu(asrc[esrc[e0 + c]] + ad);
        float m = l;
#pragma unroll
        for (int off = 16; off; off >>= 1) m = fmaxf(m, __shfl_xor(m, off, 32));
        if (c < deg) alpha[e0 + c] = __expf(l - m);
    } else {
        float m = -3e38f;
        for (int p0 = e0; p0 < e1; p0 += 32) {
            int e = p0 + c;
            if (e < e1) m = fmaxf(m, lrelu(asrc[esrc[e]] + ad));
        }
#pragma unroll
        for (int off = 16; off; off >>= 1) m = fmaxf(m, __shfl_xor(m, off, 32));
        for (int p0 = e0; p0 < e1; p0 += 32) {
            int e = p0 + c;
            if (e < e1) alpha[e] = __expf(lrelu(asrc[esrc[e]] + ad) - m);
        }
    }
}

// ---------------- agg layer 2: wave-per-node, 2 edges/iter, barrier-free ----------------

__global__ __launch_bounds__(256) void k_agg2(const float* __restrict__ h2,
                                              const int* __restrict__ row_ptr,
                                              const int* __restrict__ esrc,
                                              const float* __restrict__ alpha,
                                              const float* __restrict__ b2,
                                              float* __restrict__ out, int N) {
    __shared__ int ss[4][64];
    __shared__ float sa[4][64];
    int tid = threadIdx.x;
    int wv = tid >> 6, lane = tid & 63;
    int n = blockIdx.x * 4 + wv;
    if (n >= N) return;
    int c = lane & 31, p = lane >> 5;
    int e0 = row_ptr[n], e1 = row_ptr[n + 1];
    float acc = 0.f, asum = 0.f;

    for (int p0 = e0; p0 < e1; p0 += 64) {
        int cnt = min(64, e1 - p0);
        if (lane < cnt) {
            ss[wv][lane] = esrc[p0 + lane];
            float a = alpha[p0 + lane];
            sa[wv][lane] = a;
            asum += a;
        }
        int i = 0;
        for (; i + 3 < cnt; i += 4) {
            int s0 = ss[wv][i + p], s1 = ss[wv][i + 2 + p];
            float a0 = sa[wv][i + p], a1 = sa[wv][i + 2 + p];
            float v0 = h2[(size_t)s0 * 32 + c];
            float v1 = h2[(size_t)s1 * 32 + c];
            acc = fmaf(a0, v0, acc);
            acc = fmaf(a1, v1, acc);
        }
        for (; i + 1 < cnt; i += 2) {
            int s0 = ss[wv][i + p];
            float a0 = sa[wv][i + p];
            acc = fmaf(a0, h2[(size_t)s0 * 32 + c], acc);
        }
        if (i < cnt && p == 0) {
            int s0 = ss[wv][i];
            acc = fmaf(sa[wv][i], h2[(size_t)s0 * 32 + c], acc);
        }
    }
    acc += __shfl_xor(acc, 32);
#pragma unroll
    for (int off = 1; off < 64; off <<= 1) asum += __shfl_xor(asum, off);
    if (p == 0) out[(size_t)n * 32 + c] = acc / (asum + 1e-16f) + b2[c];
}

// ---------------- launcher ----------------

extern "C" void kernel_launch(void* const* d_in, const int* in_sizes, int n_in,
                              void* d_out, int out_size, void* d_ws, size_t ws_size,
                              hipStream_t stream) {
    const float* x   = (const float*)d_in[0];
    const int*   ei  = (const int*)d_in[1];
    const float* W1  = (const float*)d_in[2];
    const float* as1 = (const float*)d_in[3];
    const float* ad1 = (const float*)d_in[4];
    const float* b1  = (const float*)d_in[5];
    const float* W2  = (const float*)d_in[6];
    const float* as2 = (const float*)d_in[7];
    const float* ad2 = (const float*)d_in[8];
    const float* b2  = (const float*)d_in[9];
    float* out = (float*)d_out;

    const int N = in_sizes[0] / 128;   // 50000
    const int E = in_sizes[1] / 2;     // 800000
    const int* src = ei;
    const int* dstp = ei + E;
    const int nb = (N + 1023) / 1024;

    char* ws = (char*)d_ws;
    size_t off = 0;
    auto alloc = [&](size_t nbytes) {
        void* p = ws + off;
        off += (nbytes + 255) & ~(size_t)255;
        return p;
    };
    int* counts    = (int*)alloc((size_t)N * 4);
    int* row_ptr   = (int*)alloc((size_t)(N + 1) * 4);
    int* row_fill  = (int*)alloc((size_t)N * 4);
    int* esrc      = (int*)alloc((size_t)E * 4);
    float* h1      = (float*)alloc((size_t)N * 256 * 4);
    float* y1      = (float*)alloc((size_t)N * 256 * 4);
    float* h2      = (float*)alloc((size_t)N * 32 * 4);
    float* a_s1    = (float*)alloc((size_t)N * 4 * 4);
    float* a_d1    = (float*)alloc((size_t)N * 4 * 4);
    float* a_s2    = (float*)alloc((size_t)N * 4);
    float* a_d2    = (float*)alloc((size_t)N * 4);
    float* alpha1  = (float*)alloc((size_t)E * 4 * 4);
    float* alpha2  = (float*)alloc((size_t)E * 4);
    int* bsum      = (int*)alloc((size_t)nb * 4);
    int* boff      = (int*)alloc((size_t)nb * 4);

    hipMemsetAsync(counts, 0, (size_t)N * 4, stream);
    k_hist<<<(E + 255) / 256, 256, 0, stream>>>(dstp, counts, E);
    k_scan1<<<nb, 256, 0, stream>>>(counts, bsum, N);
    k_scan2<<<1, 64, 0, stream>>>(bsum, boff, &row_ptr[N], nb);
    k_scan3<<<nb, 256, 0, stream>>>(counts, boff, row_ptr, row_fill, N);
    k_scatter<<<(E + 255) / 256, 256, 0, stream>>>(src, dstp, row_fill, esrc, E);

    k_gemm1<<<dim3((N + 63) / 64, 4), 256, 0, stream>>>(x, W1, as1, ad1, h1, a_s1, a_d1, N);
    k_alpha1<<<(N + 3) / 4, 256, 0, stream>>>(a_s1, a_d1, row_ptr, esrc, alpha1, N);
    k_agg1<<<(N + 3) / 4, 256, 0, stream>>>(h1, row_ptr, esrc, alpha1, b1, y1, N);

    k_gemm2<<<(N + 31) / 32, 256, 0, stream>>>(y1, W2, as2, ad2, h2, a_s2, a_d2, N);
    k_alpha2<<<(N + 7) / 8, 256, 0, stream>>>(a_s2, a_d2, row_ptr, esrc, alpha2, N);
    k_agg2<<<(N + 3) / 4, 256, 0, stream>>>(h2, row_ptr, esrc, alpha2, b2, out, N);
}

// Round 7
// 307.207 us; speedup vs baseline: 1.8414x; 1.2084x over previous
//
#include <hip/hip_runtime.h>
#include <hip/hip_bf16.h>
#include <hip/hip_fp16.h>

#define NEG_SLOPE 0.2f

__device__ __forceinline__ float lrelu(float x) { return x >= 0.f ? x : NEG_SLOPE * x; }

__device__ __forceinline__ float4 h4_to_f4(float2 r) {
    __half2 a = *(__half2*)&r.x;
    __half2 b = *(__half2*)&r.y;
    float2 fa = __half22float2(a), fb = __half22float2(b);
    return make_float4(fa.x, fa.y, fb.x, fb.y);
}

__device__ __forceinline__ void fma4(float a, float4 v, float4& acc) {
    acc.x = fmaf(a, v.x, acc.x); acc.y = fmaf(a, v.y, acc.y);
    acc.z = fmaf(a, v.z, acc.z); acc.w = fmaf(a, v.w, acc.w);
}

// ---------------- CSR construction ----------------

__global__ void k_hist(const int* __restrict__ dst, int* __restrict__ counts, int E) {
    int e = blockIdx.x * 256 + threadIdx.x;
    if (e < E) atomicAdd(&counts[dst[e]], 1);
}

__global__ __launch_bounds__(256) void k_scan1(const int* __restrict__ counts,
                                               int* __restrict__ bsum, int N) {
    __shared__ int wsum[4];
    int b = blockIdx.x, t = threadIdx.x;
    int i0 = b * 1024 + t * 4;
    int s = 0;
    if (i0 < N) { int4 v = *(const int4*)&counts[i0]; s = v.x + v.y + v.z + v.w; }
#pragma unroll
    for (int off = 32; off; off >>= 1) s += __shfl_down(s, off);
    if ((t & 63) == 0) wsum[t >> 6] = s;
    __syncthreads();
    if (t == 0) bsum[b] = wsum[0] + wsum[1] + wsum[2] + wsum[3];
}

__global__ void k_scan2(const int* __restrict__ bsum, int* __restrict__ boff,
                        int* __restrict__ row_ptrN, int nb) {
    int t = threadIdx.x;  // 64 threads, nb <= 64
    int v = (t < nb) ? bsum[t] : 0;
    int incl = v;
#pragma unroll
    for (int off = 1; off < 64; off <<= 1) {
        int u = __shfl_up(incl, off);
        if (t >= off) incl += u;
    }
    if (t < nb) boff[t] = incl - v;
    if (t == nb - 1) *row_ptrN = incl;
}

__global__ __launch_bounds__(256) void k_scan3(const int* __restrict__ counts,
                                               const int* __restrict__ boff,
                                               int* __restrict__ row_ptr,
                                               int* __restrict__ row_fill, int N) {
    __shared__ int lds[256];
    int b = blockIdx.x, t = threadIdx.x;
    int i0 = b * 1024 + t * 4;
    int4 v = make_int4(0, 0, 0, 0);
    if (i0 < N) v = *(const int4*)&counts[i0];
    int tot = v.x + v.y + v.z + v.w;
    lds[t] = tot;
    __syncthreads();
    for (int off = 1; off < 256; off <<= 1) {
        int u = (t >= off) ? lds[t - off] : 0;
        __syncthreads();
        lds[t] += u;
        __syncthreads();
    }
    int excl = lds[t] - tot;
    int run = boff[b] + excl;
    if (i0 < N) {
        row_ptr[i0] = run;     row_fill[i0] = run;     run += v.x;
        row_ptr[i0 + 1] = run; row_fill[i0 + 1] = run; run += v.y;
        row_ptr[i0 + 2] = run; row_fill[i0 + 2] = run; run += v.z;
        row_ptr[i0 + 3] = run; row_fill[i0 + 3] = run;
    }
}

__global__ void k_scatter(const int* __restrict__ src, const int* __restrict__ dst,
                          int* __restrict__ row_fill, int* __restrict__ esrc, int E) {
    int e = blockIdx.x * 256 + threadIdx.x;
    if (e < E) {
        int p = atomicAdd(&row_fill[dst[e]], 1);
        esrc[p] = src[e];
    }
}

// ---------------- GEMM1: h1 = x @ W1  [M,128]@[128,256], fp16 out, fused att dots ----------------

__global__ __launch_bounds__(256) void k_gemm1(const float* __restrict__ x,
                                               const float* __restrict__ W,
                                               const float* __restrict__ att_src,
                                               const float* __restrict__ att_dst,
                                               __half* __restrict__ h,
                                               float* __restrict__ a_s,
                                               float* __restrict__ a_d, int M) {
    __shared__ float xs[128][64];   // xs[k][m]
    __shared__ float ws[128][64];   // ws[k][c]
    const int tid = threadIdx.x;
    const int row0 = blockIdx.x * 64;
    const int hh = blockIdx.y;           // head == 64-col tile
    const int col0 = hh * 64;

    for (int t = tid; t < 2048; t += 256) {
        int k4 = t >> 6, m = t & 63;
        int r = row0 + m;
        float4 v = make_float4(0.f, 0.f, 0.f, 0.f);
        if (r < M) v = *(const float4*)&x[(size_t)r * 128 + k4 * 4];
        xs[k4 * 4 + 0][m] = v.x;
        xs[k4 * 4 + 1][m] = v.y;
        xs[k4 * 4 + 2][m] = v.z;
        xs[k4 * 4 + 3][m] = v.w;
    }
    for (int t = tid; t < 2048; t += 256) {
        int k = t >> 4, c4 = t & 15;
        *(float4*)&ws[k][c4 * 4] = *(const float4*)&W[(size_t)k * 256 + col0 + c4 * 4];
    }
    __syncthreads();

    const int tx = tid & 15, ty = tid >> 4;
    float acc[4][4] = {};
#pragma unroll 4
    for (int k = 0; k < 128; ++k) {
        float4 a = *(const float4*)&xs[k][ty * 4];
        float4 b = *(const float4*)&ws[k][tx * 4];
        float av[4] = {a.x, a.y, a.z, a.w};
        float bv[4] = {b.x, b.y, b.z, b.w};
#pragma unroll
        for (int i = 0; i < 4; ++i)
#pragma unroll
            for (int j = 0; j < 4; ++j) acc[i][j] += av[i] * bv[j];
    }

    float asv[4], adv[4];
#pragma unroll
    for (int j = 0; j < 4; ++j) {
        asv[j] = att_src[col0 + tx * 4 + j];
        adv[j] = att_dst[col0 + tx * 4 + j];
    }
#pragma unroll
    for (int i = 0; i < 4; ++i) {
        int r = row0 + ty * 4 + i;
        if (r < M) {
            __half2 p01 = __floats2half2_rn(acc[i][0], acc[i][1]);
            __half2 p23 = __floats2half2_rn(acc[i][2], acc[i][3]);
            float2 st;
            *(__half2*)&st.x = p01;
            *(__half2*)&st.y = p23;
            *(float2*)&h[(size_t)r * 256 + col0 + tx * 4] = st;
        }
        float s_ = 0.f, d_ = 0.f;
#pragma unroll
        for (int j = 0; j < 4; ++j) {
            s_ = fmaf(acc[i][j], asv[j], s_);
            d_ = fmaf(acc[i][j], adv[j], d_);
        }
#pragma unroll
        for (int off = 1; off < 16; off <<= 1) {
            s_ += __shfl_xor(s_, off);
            d_ += __shfl_xor(d_, off);
        }
        if (tx == 0 && r < M) {
            a_s[(size_t)r * 4 + hh] = s_;
            a_d[(size_t)r * 4 + hh] = d_;
        }
    }
}

// ---------------- alpha layer 1: p = exp(l - max) per edge, CSR order ----------------

__global__ __launch_bounds__(256) void k_alpha1(const float* __restrict__ asrc,
                                                const float* __restrict__ adst,
                                                const int* __restrict__ row_ptr,
                                                const int* __restrict__ esrc,
                                                float* __restrict__ alpha, int N) {
    int wv = threadIdx.x >> 6, lane = threadIdx.x & 63;
    int n = blockIdx.x * 4 + wv;
    if (n >= N) return;
    int e0 = row_ptr[n], e1 = row_ptr[n + 1];
    int deg = e1 - e0;
    if (deg == 0) return;
    const float4 ad = *(const float4*)&adst[(size_t)n * 4];
    if (deg <= 64) {
        float4 l = make_float4(-3e38f, -3e38f, -3e38f, -3e38f);
        if (lane < deg) {
            int s = esrc[e0 + lane];
            float4 as = *(const float4*)&asrc[(size_t)s * 4];
            l.x = lrelu(as.x + ad.x); l.y = lrelu(as.y + ad.y);
            l.z = lrelu(as.z + ad.z); l.w = lrelu(as.w + ad.w);
        }
        float4 m = l;
#pragma unroll
        for (int off = 32; off; off >>= 1) {
            m.x = fmaxf(m.x, __shfl_xor(m.x, off));
            m.y = fmaxf(m.y, __shfl_xor(m.y, off));
            m.z = fmaxf(m.z, __shfl_xor(m.z, off));
            m.w = fmaxf(m.w, __shfl_xor(m.w, off));
        }
        if (lane < deg) {
            float4 p;
            p.x = __expf(l.x - m.x); p.y = __expf(l.y - m.y);
            p.z = __expf(l.z - m.z); p.w = __expf(l.w - m.w);
            *(float4*)&alpha[(size_t)(e0 + lane) * 4] = p;
        }
    } else {
        float4 m = make_float4(-3e38f, -3e38f, -3e38f, -3e38f);
        for (int p0 = e0; p0 < e1; p0 += 64) {
            int e = p0 + lane;
            if (e < e1) {
                int s = esrc[e];
                float4 as = *(const float4*)&asrc[(size_t)s * 4];
                m.x = fmaxf(m.x, lrelu(as.x + ad.x));
                m.y = fmaxf(m.y, lrelu(as.y + ad.y));
                m.z = fmaxf(m.z, lrelu(as.z + ad.z));
                m.w = fmaxf(m.w, lrelu(as.w + ad.w));
            }
        }
#pragma unroll
        for (int off = 32; off; off >>= 1) {
            m.x = fmaxf(m.x, __shfl_xor(m.x, off));
            m.y = fmaxf(m.y, __shfl_xor(m.y, off));
            m.z = fmaxf(m.z, __shfl_xor(m.z, off));
            m.w = fmaxf(m.w, __shfl_xor(m.w, off));
        }
        for (int p0 = e0; p0 < e1; p0 += 64) {
            int e = p0 + lane;
            if (e < e1) {
                int s = esrc[e];
                float4 as = *(const float4*)&asrc[(size_t)s * 4];
                float4 p;
                p.x = __expf(lrelu(as.x + ad.x) - m.x);
                p.y = __expf(lrelu(as.y + ad.y) - m.y);
                p.z = __expf(lrelu(as.z + ad.z) - m.z);
                p.w = __expf(lrelu(as.w + ad.w) - m.w);
                *(float4*)&alpha[(size_t)e * 4] = p;
            }
        }
    }
}

// ---------------- agg layer 1: wave-per-node, fp16 gather, x4 unroll ----------------

__global__ __launch_bounds__(256) void k_agg1(const __half* __restrict__ h1,
                                              const int* __restrict__ row_ptr,
                                              const int* __restrict__ esrc,
                                              const float* __restrict__ alpha,
                                              const float* __restrict__ b1,
                                              float* __restrict__ y1, int N) {
    __shared__ int ss[4][64];
    __shared__ float sa[4][64 * 4];
    int tid = threadIdx.x;
    int wv = tid >> 6, lane = tid & 63;
    int n = blockIdx.x * 4 + wv;
    if (n >= N) return;
    int head = lane >> 4;                 // channels lane*4..lane*4+3 all in head lane/16
    int e0 = row_ptr[n], e1 = row_ptr[n + 1];
    float4 acc = make_float4(0.f, 0.f, 0.f, 0.f);
    float4 asum = make_float4(0.f, 0.f, 0.f, 0.f);

    for (int p0 = e0; p0 < e1; p0 += 64) {
        int cnt = min(64, e1 - p0);
        if (lane < cnt) {
            ss[wv][lane] = esrc[p0 + lane];
            float4 a4 = *(const float4*)&alpha[(size_t)(p0 + lane) * 4];
            *(float4*)&sa[wv][lane * 4] = a4;
            asum.x += a4.x; asum.y += a4.y; asum.z += a4.z; asum.w += a4.w;
        }
        // same-wave LDS write->read is in program order: no barrier needed
        int i = 0;
        for (; i + 3 < cnt; i += 4) {
            int s0 = ss[wv][i], s1 = ss[wv][i + 1], s2 = ss[wv][i + 2], s3 = ss[wv][i + 3];
            float a0 = sa[wv][i * 4 + head],       a1 = sa[wv][(i + 1) * 4 + head];
            float a2 = sa[wv][(i + 2) * 4 + head], a3 = sa[wv][(i + 3) * 4 + head];
            float2 r0 = *(const float2*)&h1[(size_t)s0 * 256 + lane * 4];
            float2 r1 = *(const float2*)&h1[(size_t)s1 * 256 + lane * 4];
            float2 r2 = *(const float2*)&h1[(size_t)s2 * 256 + lane * 4];
            float2 r3 = *(const float2*)&h1[(size_t)s3 * 256 + lane * 4];
            fma4(a0, h4_to_f4(r0), acc);
            fma4(a1, h4_to_f4(r1), acc);
            fma4(a2, h4_to_f4(r2), acc);
            fma4(a3, h4_to_f4(r3), acc);
        }
        for (; i < cnt; ++i) {
            int s0 = ss[wv][i];
            float a0 = sa[wv][i * 4 + head];
            float2 r0 = *(const float2*)&h1[(size_t)s0 * 256 + lane * 4];
            fma4(a0, h4_to_f4(r0), acc);
        }
    }

#pragma unroll
    for (int off = 1; off < 64; off <<= 1) {
        asum.x += __shfl_xor(asum.x, off);
        asum.y += __shfl_xor(asum.y, off);
        asum.z += __shfl_xor(asum.z, off);
        asum.w += __shfl_xor(asum.w, off);
    }
    float ssum = (head == 0) ? asum.x : (head == 1) ? asum.y : (head == 2) ? asum.z : asum.w;
    float inv = 1.f / (ssum + 1e-16f);
    float4 bb = *(const float4*)&b1[lane * 4];
    float4 v;
    v.x = acc.x * inv + bb.x; v.y = acc.y * inv + bb.y;
    v.z = acc.z * inv + bb.z; v.w = acc.w * inv + bb.w;
    v.x = (v.x > 0.f) ? v.x : (__expf(v.x) - 1.f);
    v.y = (v.y > 0.f) ? v.y : (__expf(v.y) - 1.f);
    v.z = (v.z > 0.f) ? v.z : (__expf(v.z) - 1.f);
    v.w = (v.w > 0.f) ? v.w : (__expf(v.w) - 1.f);
    *(float4*)&y1[(size_t)n * 256 + lane * 4] = v;
}

// ---------------- GEMM2: h2 = y1 @ W2  [M,256]@[256,32], fp16 out, fused att dots ----------------

__global__ __launch_bounds__(256) void k_gemm2(const float* __restrict__ y1,
                                               const float* __restrict__ W,
                                               const float* __restrict__ att_src,
                                               const float* __restrict__ att_dst,
                                               __half* __restrict__ h2,
                                               float* __restrict__ a_s,
                                               float* __restrict__ a_d, int M) {
    __shared__ float xs[256][32];
    __shared__ float ws2[256 * 32];
    int tid = threadIdx.x;
    int row0 = blockIdx.x * 32;
    for (int t = tid; t < 2048; t += 256) {
        int k4 = t >> 5, m = t & 31;
        int r = row0 + m;
        float4 v = make_float4(0.f, 0.f, 0.f, 0.f);
        if (r < M) v = *(const float4*)&y1[(size_t)r * 256 + k4 * 4];
        xs[k4 * 4 + 0][m] = v.x;
        xs[k4 * 4 + 1][m] = v.y;
        xs[k4 * 4 + 2][m] = v.z;
        xs[k4 * 4 + 3][m] = v.w;
    }
    for (int t = tid; t < 2048; t += 256)
        *(float4*)&ws2[t * 4] = *(const float4*)&W[t * 4];
    __syncthreads();

    int tx = tid & 7, ty = tid >> 3;
    float acc[4] = {};
#pragma unroll 4
    for (int k = 0; k < 256; ++k) {
        float a = xs[k][ty];
        float4 b = *(const float4*)&ws2[k * 32 + tx * 4];
        acc[0] += a * b.x; acc[1] += a * b.y; acc[2] += a * b.z; acc[3] += a * b.w;
    }
    int r = row0 + ty;
    if (r < M) {
        __half2 p01 = __floats2half2_rn(acc[0], acc[1]);
        __half2 p23 = __floats2half2_rn(acc[2], acc[3]);
        float2 st;
        *(__half2*)&st.x = p01;
        *(__half2*)&st.y = p23;
        *(float2*)&h2[(size_t)r * 32 + tx * 4] = st;
    }

    float s_ = 0.f, d_ = 0.f;
#pragma unroll
    for (int j = 0; j < 4; ++j) {
        s_ = fmaf(acc[j], att_src[tx * 4 + j], s_);
        d_ = fmaf(acc[j], att_dst[tx * 4 + j], d_);
    }
#pragma unroll
    for (int off = 1; off < 8; off <<= 1) {
        s_ += __shfl_xor(s_, off);
        d_ += __shfl_xor(d_, off);
    }
    if (tx == 0 && r < M) { a_s[r] = s_; a_d[r] = d_; }
}

// ---------------- alpha layer 2 ----------------

__global__ __launch_bounds__(256) void k_alpha2(const float* __restrict__ asrc,
                                                const float* __restrict__ adst,
                                                const int* __restrict__ row_ptr,
                                                const int* __restrict__ esrc,
                                                float* __restrict__ alpha, int N) {
    int g = threadIdx.x >> 5, c = threadIdx.x & 31;
    int n = blockIdx.x * 8 + g;
    if (n >= N) return;
    int e0 = row_ptr[n], e1 = row_ptr[n + 1];
    int deg = e1 - e0;
    if (deg == 0) return;
    float ad = adst[n];
    if (deg <= 32) {
        float l = -3e38f;
        if (c < deg) l = lrelu(asrc[esrc[e0 + c]] + ad);
        float m = l;
#pragma unroll
        for (int off = 16; off; off >>= 1) m = fmaxf(m, __shfl_xor(m, off, 32));
        if (c < deg) alpha[e0 + c] = __expf(l - m);
    } else {
        float m = -3e38f;
        for (int p0 = e0; p0 < e1; p0 += 32) {
            int e = p0 + c;
            if (e < e1) m = fmaxf(m, lrelu(asrc[esrc[e]] + ad));
        }
#pragma unroll
        for (int off = 16; off; off >>= 1) m = fmaxf(m, __shfl_xor(m, off, 32));
        for (int p0 = e0; p0 < e1; p0 += 32) {
            int e = p0 + c;
            if (e < e1) alpha[e] = __expf(lrelu(asrc[esrc[e]] + ad) - m);
        }
    }
}

// ---------------- agg layer 2: wave-per-node, fp16 gather, 4 edges x 16 lanes ----------------

__global__ __launch_bounds__(256) void k_agg2(const __half* __restrict__ h2,
                                              const int* __restrict__ row_ptr,
                                              const int* __restrict__ esrc,
                                              const float* __restrict__ alpha,
                                              const float* __restrict__ b2,
                                              float* __restrict__ out, int N) {
    __shared__ int ss[4][64];
    __shared__ float sa[4][64];
    int tid = threadIdx.x;
    int wv = tid >> 6, lane = tid & 63;
    int n = blockIdx.x * 4 + wv;
    if (n >= N) return;
    int grp = lane >> 4, cl = lane & 15;   // edge group, channel pair index
    int e0 = row_ptr[n], e1 = row_ptr[n + 1];
    float2 acc = make_float2(0.f, 0.f);
    float asum = 0.f;

    for (int p0 = e0; p0 < e1; p0 += 64) {
        int cnt = min(64, e1 - p0);
        if (lane < cnt) {
            ss[wv][lane] = esrc[p0 + lane];
            float a = alpha[p0 + lane];
            sa[wv][lane] = a;
            asum += a;
        }
        int i = 0;
        for (; i + 7 < cnt; i += 8) {
            int ea = i + grp, eb = i + 4 + grp;
            int s0 = ss[wv][ea], s1 = ss[wv][eb];
            float a0 = sa[wv][ea], a1 = sa[wv][eb];
            __half2 v0 = *(const __half2*)&h2[(size_t)s0 * 32 + cl * 2];
            __half2 v1 = *(const __half2*)&h2[(size_t)s1 * 32 + cl * 2];
            float2 f0 = __half22float2(v0), f1 = __half22float2(v1);
            acc.x = fmaf(a0, f0.x, acc.x); acc.y = fmaf(a0, f0.y, acc.y);
            acc.x = fmaf(a1, f1.x, acc.x); acc.y = fmaf(a1, f1.y, acc.y);
        }
        for (; i < cnt; i += 4) {
            int e = i + grp;
            if (e < cnt) {
                int s0 = ss[wv][e];
                float a0 = sa[wv][e];
                __half2 v0 = *(const __half2*)&h2[(size_t)s0 * 32 + cl * 2];
                float2 f0 = __half22float2(v0);
                acc.x = fmaf(a0, f0.x, acc.x); acc.y = fmaf(a0, f0.y, acc.y);
            }
        }
    }
    // sum partial edge-group accumulators (groups differ in lane bits 4,5)
    acc.x += __shfl_xor(acc.x, 16); acc.y += __shfl_xor(acc.y, 16);
    acc.x += __shfl_xor(acc.x, 32); acc.y += __shfl_xor(acc.y, 32);
#pragma unroll
    for (int off = 1; off < 64; off <<= 1) asum += __shfl_xor(asum, off);
    if (grp == 0) {
        float inv = 1.f / (asum + 1e-16f);
        float2 o;
        o.x = acc.x * inv + b2[cl * 2];
        o.y = acc.y * inv + b2[cl * 2 + 1];
        *(float2*)&out[(size_t)n * 32 + cl * 2] = o;
    }
}

// ---------------- launcher ----------------

extern "C" void kernel_launch(void* const* d_in, const int* in_sizes, int n_in,
                              void* d_out, int out_size, void* d_ws, size_t ws_size,
                              hipStream_t stream) {
    const float* x   = (const float*)d_in[0];
    const int*   ei  = (const int*)d_in[1];
    const float* W1  = (const float*)d_in[2];
    const float* as1 = (const float*)d_in[3];
    const float* ad1 = (const float*)d_in[4];
    const float* b1  = (const float*)d_in[5];
    const float* W2  = (const float*)d_in[6];
    const float* as2 = (const float*)d_in[7];
    const float* ad2 = (const float*)d_in[8];
    const float* b2  = (const float*)d_in[9];
    float* out = (float*)d_out;

    const int N = in_sizes[0] / 128;   // 50000
    const int E = in_sizes[1] / 2;     // 800000
    const int* src = ei;
    const int* dstp = ei + E;
    const int nb = (N + 1023) / 1024;

    char* ws = (char*)d_ws;
    size_t off = 0;
    auto alloc = [&](size_t nbytes) {
        void* p = ws + off;
        off += (nbytes + 255) & ~(size_t)255;
        return p;
    };
    int* counts    = (int*)alloc((size_t)N * 4);
    int* row_ptr   = (int*)alloc((size_t)(N + 1) * 4);
    int* row_fill  = (int*)alloc((size_t)N * 4);
    int* esrc      = (int*)alloc((size_t)E * 4);
    __half* h1     = (__half*)alloc((size_t)N * 256 * 2);
    float* y1      = (float*)alloc((size_t)N * 256 * 4);
    __half* h2     = (__half*)alloc((size_t)N * 32 * 2);
    float* a_s1    = (float*)alloc((size_t)N * 4 * 4);
    float* a_d1    = (float*)alloc((size_t)N * 4 * 4);
    float* a_s2    = (float*)alloc((size_t)N * 4);
    float* a_d2    = (float*)alloc((size_t)N * 4);
    float* alpha1  = (float*)alloc((size_t)E * 4 * 4);
    float* alpha2  = (float*)alloc((size_t)E * 4);
    int* bsum      = (int*)alloc((size_t)nb * 4);
    int* boff      = (int*)alloc((size_t)nb * 4);

    hipMemsetAsync(counts, 0, (size_t)N * 4, stream);
    k_hist<<<(E + 255) / 256, 256, 0, stream>>>(dstp, counts, E);
    k_scan1<<<nb, 256, 0, stream>>>(counts, bsum, N);
    k_scan2<<<1, 64, 0, stream>>>(bsum, boff, &row_ptr[N], nb);
    k_scan3<<<nb, 256, 0, stream>>>(counts, boff, row_ptr, row_fill, N);
    k_scatter<<<(E + 255) / 256, 256, 0, stream>>>(src, dstp, row_fill, esrc, E);

    k_gemm1<<<dim3((N + 63) / 64, 4), 256, 0, stream>>>(x, W1, as1, ad1, h1, a_s1, a_d1, N);
    k_alpha1<<<(N + 3) / 4, 256, 0, stream>>>(a_s1, a_d1, row_ptr, esrc, alpha1, N);
    k_agg1<<<(N + 3) / 4, 256, 0, stream>>>(h1, row_ptr, esrc, alpha1, b1, y1, N);

    k_gemm2<<<(N + 31) / 32, 256, 0, stream>>>(y1, W2, as2, ad2, h2, a_s2, a_d2, N);
    k_alpha2<<<(N + 7) / 8, 256, 0, stream>>>(a_s2, a_d2, row_ptr, esrc, alpha2, N);
    k_agg2<<<(N + 3) / 4, 256, 0, stream>>>(h2, row_ptr, esrc, alpha2, b2, out, N);
}

// Round 8
// 267.234 us; speedup vs baseline: 2.1169x; 1.1496x over previous
//
#include <hip/hip_runtime.h>
#include <hip/hip_bf16.h>
#include <hip/hip_fp16.h>

#define NEG_SLOPE 0.2f

typedef _Float16 half8 __attribute__((ext_vector_type(8)));
typedef float f32x4 __attribute__((ext_vector_type(4)));

__device__ __forceinline__ float lrelu(float x) { return x >= 0.f ? x : NEG_SLOPE * x; }

__device__ __forceinline__ float4 h4_to_f4(float2 r) {
    __half2 a = *(__half2*)&r.x;
    __half2 b = *(__half2*)&r.y;
    float2 fa = __half22float2(a), fb = __half22float2(b);
    return make_float4(fa.x, fa.y, fb.x, fb.y);
}

__device__ __forceinline__ void fma4(float a, float4 v, float4& acc) {
    acc.x = fmaf(a, v.x, acc.x); acc.y = fmaf(a, v.y, acc.y);
    acc.z = fmaf(a, v.z, acc.z); acc.w = fmaf(a, v.w, acc.w);
}

// ---------------- CSR construction ----------------

__global__ void k_hist(const int* __restrict__ dst, int* __restrict__ counts, int E) {
    int e = blockIdx.x * 256 + threadIdx.x;
    if (e < E) atomicAdd(&counts[dst[e]], 1);
}

__global__ __launch_bounds__(256) void k_scan1(const int* __restrict__ counts,
                                               int* __restrict__ bsum, int N) {
    __shared__ int wsum[4];
    int b = blockIdx.x, t = threadIdx.x;
    int i0 = b * 1024 + t * 4;
    int s = 0;
    if (i0 < N) { int4 v = *(const int4*)&counts[i0]; s = v.x + v.y + v.z + v.w; }
#pragma unroll
    for (int off = 32; off; off >>= 1) s += __shfl_down(s, off);
    if ((t & 63) == 0) wsum[t >> 6] = s;
    __syncthreads();
    if (t == 0) bsum[b] = wsum[0] + wsum[1] + wsum[2] + wsum[3];
}

__global__ void k_scan2(const int* __restrict__ bsum, int* __restrict__ boff,
                        int* __restrict__ row_ptrN, int nb) {
    int t = threadIdx.x;  // 64 threads, nb <= 64
    int v = (t < nb) ? bsum[t] : 0;
    int incl = v;
#pragma unroll
    for (int off = 1; off < 64; off <<= 1) {
        int u = __shfl_up(incl, off);
        if (t >= off) incl += u;
    }
    if (t < nb) boff[t] = incl - v;
    if (t == nb - 1) *row_ptrN = incl;
}

__global__ __launch_bounds__(256) void k_scan3(const int* __restrict__ counts,
                                               const int* __restrict__ boff,
                                               int* __restrict__ row_ptr,
                                               int* __restrict__ row_fill, int N) {
    __shared__ int lds[256];
    int b = blockIdx.x, t = threadIdx.x;
    int i0 = b * 1024 + t * 4;
    int4 v = make_int4(0, 0, 0, 0);
    if (i0 < N) v = *(const int4*)&counts[i0];
    int tot = v.x + v.y + v.z + v.w;
    lds[t] = tot;
    __syncthreads();
    for (int off = 1; off < 256; off <<= 1) {
        int u = (t >= off) ? lds[t - off] : 0;
        __syncthreads();
        lds[t] += u;
        __syncthreads();
    }
    int excl = lds[t] - tot;
    int run = boff[b] + excl;
    if (i0 < N) {
        row_ptr[i0] = run;     row_fill[i0] = run;     run += v.x;
        row_ptr[i0 + 1] = run; row_fill[i0 + 1] = run; run += v.y;
        row_ptr[i0 + 2] = run; row_fill[i0 + 2] = run; run += v.z;
        row_ptr[i0 + 3] = run; row_fill[i0 + 3] = run;
    }
}

__global__ void k_scatter(const int* __restrict__ src, const int* __restrict__ dst,
                          int* __restrict__ row_fill, int* __restrict__ esrc, int E) {
    int e = blockIdx.x * 256 + threadIdx.x;
    if (e < E) {
        int p = atomicAdd(&row_fill[dst[e]], 1);
        esrc[p] = src[e];
    }
}

// ---------------- W1 transpose to fp16: Wt[n=256][k=128] ----------------

__global__ __launch_bounds__(128) void k_w1t(const float* __restrict__ W,
                                             __half* __restrict__ Wt) {
    int n = blockIdx.x;       // 256
    int k = threadIdx.x;      // 128
    Wt[n * 128 + k] = __float2half(W[(size_t)k * 256 + n]);
}

// ---------------- GEMM1 (MFMA fp16): h1 = x @ W1, fused att dots ----------------
// block: 64 rows x 128 cols (2 heads), 4 waves; wave w -> m-tile w (16 rows), 8 n-tiles.

__global__ __launch_bounds__(256, 3) void k_gemm1(const float* __restrict__ x,
                                                  const __half* __restrict__ Wt,
                                                  const float* __restrict__ att_src,
                                                  const float* __restrict__ att_dst,
                                                  __half* __restrict__ h,
                                                  float* __restrict__ a_s,
                                                  float* __restrict__ a_d, int M) {
    __shared__ __align__(16) __half Xs[64 * 128];    // [row][k], XOR-swizzled 16B chunks
    __shared__ __align__(16) __half Ws[128 * 128];   // [n][k], XOR-swizzled 16B chunks
    const int tid = threadIdx.x;
    const int row0 = blockIdx.x * 64;
    const int by = blockIdx.y;            // 0..1 -> cols by*128..by*128+127
    const int col0 = by * 128;

    // stage X: 64 rows x 16 chunks (16B = 8 fp16), fp32->fp16
    for (int t = 0; t < 4; ++t) {
        int c = tid + t * 256;            // 0..1023
        int row = c >> 4, ch = c & 15;
        int r = row0 + row;
        float4 va = make_float4(0.f, 0.f, 0.f, 0.f), vb = va;
        if (r < M) {
            va = *(const float4*)&x[(size_t)r * 128 + ch * 8];
            vb = *(const float4*)&x[(size_t)r * 128 + ch * 8 + 4];
        }
        half8 hv;
        hv[0] = (_Float16)va.x; hv[1] = (_Float16)va.y;
        hv[2] = (_Float16)va.z; hv[3] = (_Float16)va.w;
        hv[4] = (_Float16)vb.x; hv[5] = (_Float16)vb.y;
        hv[6] = (_Float16)vb.z; hv[7] = (_Float16)vb.w;
        *(half8*)((char*)Xs + row * 256 + ((ch * 16) ^ ((row & 7) << 4))) = hv;
    }
    // stage Wt rows col0..col0+127: 128 rows x 16 chunks
    for (int t = 0; t < 8; ++t) {
        int c = tid + t * 256;            // 0..2047
        int n = c >> 4, ch = c & 15;
        float4 v = *(const float4*)&Wt[(size_t)(col0 + n) * 128 + ch * 8];
        *(float4*)((char*)Ws + n * 256 + ((ch * 16) ^ ((n & 7) << 4))) = v;
    }
    __syncthreads();

    const int w = tid >> 6, lane = tid & 63;
    const int col_l = lane & 15, kgrp = lane >> 4;
    const int arow = w * 16 + col_l;
    const int sw = (col_l & 7) << 4;

    f32x4 acc[8];
#pragma unroll
    for (int nt = 0; nt < 8; ++nt) acc[nt] = (f32x4){0.f, 0.f, 0.f, 0.f};

#pragma unroll
    for (int ks = 0; ks < 4; ++ks) {
        int kchunk = (ks * 4 + kgrp) * 16;     // byte offset of 16B chunk along k
        half8 av = *(const half8*)((const char*)Xs + arow * 256 + (kchunk ^ sw));
#pragma unroll
        for (int nt = 0; nt < 8; ++nt) {
            half8 bv = *(const half8*)((const char*)Ws + (nt * 16 + col_l) * 256 + (kchunk ^ sw));
            acc[nt] = __builtin_amdgcn_mfma_f32_16x16x32_f16(av, bv, acc[nt], 0, 0, 0);
        }
    }

    // epilogue: C layout col=lane&15, row=(lane>>4)*4+reg
    float asv[8], adv[8];
#pragma unroll
    for (int nt = 0; nt < 8; ++nt) {
        int gc = col0 + nt * 16 + col_l;
        asv[nt] = att_src[gc];
        adv[nt] = att_dst[gc];
    }
    const int rbase = row0 + w * 16 + kgrp * 4;
#pragma unroll
    for (int reg = 0; reg < 4; ++reg) {
        int gr = rbase + reg;
        if (gr < M) {
#pragma unroll
            for (int nt = 0; nt < 8; ++nt)
                h[(size_t)gr * 256 + col0 + nt * 16 + col_l] = __float2half(acc[nt][reg]);
        }
        float s0 = 0.f, d0 = 0.f, s1 = 0.f, d1 = 0.f;
#pragma unroll
        for (int nt = 0; nt < 4; ++nt) {
            s0 = fmaf(acc[nt][reg], asv[nt], s0);
            d0 = fmaf(acc[nt][reg], adv[nt], d0);
            s1 = fmaf(acc[nt + 4][reg], asv[nt + 4], s1);
            d1 = fmaf(acc[nt + 4][reg], adv[nt + 4], d1);
        }
#pragma unroll
        for (int off = 1; off < 16; off <<= 1) {
            s0 += __shfl_xor(s0, off); d0 += __shfl_xor(d0, off);
            s1 += __shfl_xor(s1, off); d1 += __shfl_xor(d1, off);
        }
        if (col_l == 0 && gr < M) {
            a_s[(size_t)gr * 4 + by * 2]     = s0;
            a_s[(size_t)gr * 4 + by * 2 + 1] = s1;
            a_d[(size_t)gr * 4 + by * 2]     = d0;
            a_d[(size_t)gr * 4 + by * 2 + 1] = d1;
        }
    }
}

// ---------------- alpha layer 1: p = exp(l - max) per edge, CSR order ----------------

__global__ __launch_bounds__(256) void k_alpha1(const float* __restrict__ asrc,
                                                const float* __restrict__ adst,
                                                const int* __restrict__ row_ptr,
                                                const int* __restrict__ esrc,
                                                float* __restrict__ alpha, int N) {
    int wv = threadIdx.x >> 6, lane = threadIdx.x & 63;
    int n = blockIdx.x * 4 + wv;
    if (n >= N) return;
    int e0 = row_ptr[n], e1 = row_ptr[n + 1];
    int deg = e1 - e0;
    if (deg == 0) return;
    const float4 ad = *(const float4*)&adst[(size_t)n * 4];
    if (deg <= 64) {
        float4 l = make_float4(-3e38f, -3e38f, -3e38f, -3e38f);
        if (lane < deg) {
            int s = esrc[e0 + lane];
            float4 as = *(const float4*)&asrc[(size_t)s * 4];
            l.x = lrelu(as.x + ad.x); l.y = lrelu(as.y + ad.y);
            l.z = lrelu(as.z + ad.z); l.w = lrelu(as.w + ad.w);
        }
        float4 m = l;
#pragma unroll
        for (int off = 32; off; off >>= 1) {
            m.x = fmaxf(m.x, __shfl_xor(m.x, off));
            m.y = fmaxf(m.y, __shfl_xor(m.y, off));
            m.z = fmaxf(m.z, __shfl_xor(m.z, off));
            m.w = fmaxf(m.w, __shfl_xor(m.w, off));
        }
        if (lane < deg) {
            float4 p;
            p.x = __expf(l.x - m.x); p.y = __expf(l.y - m.y);
            p.z = __expf(l.z - m.z); p.w = __expf(l.w - m.w);
            *(float4*)&alpha[(size_t)(e0 + lane) * 4] = p;
        }
    } else {
        float4 m = make_float4(-3e38f, -3e38f, -3e38f, -3e38f);
        for (int p0 = e0; p0 < e1; p0 += 64) {
            int e = p0 + lane;
            if (e < e1) {
                int s = esrc[e];
                float4 as = *(const float4*)&asrc[(size_t)s * 4];
                m.x = fmaxf(m.x, lrelu(as.x + ad.x));
                m.y = fmaxf(m.y, lrelu(as.y + ad.y));
                m.z = fmaxf(m.z, lrelu(as.z + ad.z));
                m.w = fmaxf(m.w, lrelu(as.w + ad.w));
            }
        }
#pragma unroll
        for (int off = 32; off; off >>= 1) {
            m.x = fmaxf(m.x, __shfl_xor(m.x, off));
            m.y = fmaxf(m.y, __shfl_xor(m.y, off));
            m.z = fmaxf(m.z, __shfl_xor(m.z, off));
            m.w = fmaxf(m.w, __shfl_xor(m.w, off));
        }
        for (int p0 = e0; p0 < e1; p0 += 64) {
            int e = p0 + lane;
            if (e < e1) {
                int s = esrc[e];
                float4 as = *(const float4*)&asrc[(size_t)s * 4];
                float4 p;
                p.x = __expf(lrelu(as.x + ad.x) - m.x);
                p.y = __expf(lrelu(as.y + ad.y) - m.y);
                p.z = __expf(lrelu(as.z + ad.z) - m.z);
                p.w = __expf(lrelu(as.w + ad.w) - m.w);
                *(float4*)&alpha[(size_t)e * 4] = p;
            }
        }
    }
}

// ---------------- agg layer 1: wave-per-node, fp16 gather, x4 unroll ----------------

__global__ __launch_bounds__(256) void k_agg1(const __half* __restrict__ h1,
                                              const int* __restrict__ row_ptr,
                                              const int* __restrict__ esrc,
                                              const float* __restrict__ alpha,
                                              const float* __restrict__ b1,
                                              float* __restrict__ y1, int N) {
    __shared__ int ss[4][64];
    __shared__ float sa[4][64 * 4];
    int tid = threadIdx.x;
    int wv = tid >> 6, lane = tid & 63;
    int n = blockIdx.x * 4 + wv;
    if (n >= N) return;
    int head = lane >> 4;                 // channels lane*4..lane*4+3 all in head lane/16
    int e0 = row_ptr[n], e1 = row_ptr[n + 1];
    float4 acc = make_float4(0.f, 0.f, 0.f, 0.f);
    float4 asum = make_float4(0.f, 0.f, 0.f, 0.f);

    for (int p0 = e0; p0 < e1; p0 += 64) {
        int cnt = min(64, e1 - p0);
        if (lane < cnt) {
            ss[wv][lane] = esrc[p0 + lane];
            float4 a4 = *(const float4*)&alpha[(size_t)(p0 + lane) * 4];
            *(float4*)&sa[wv][lane * 4] = a4;
            asum.x += a4.x; asum.y += a4.y; asum.z += a4.z; asum.w += a4.w;
        }
        // same-wave LDS write->read is in program order: no barrier needed
        int i = 0;
        for (; i + 3 < cnt; i += 4) {
            int s0 = ss[wv][i], s1 = ss[wv][i + 1], s2 = ss[wv][i + 2], s3 = ss[wv][i + 3];
            float a0 = sa[wv][i * 4 + head],       a1 = sa[wv][(i + 1) * 4 + head];
            float a2 = sa[wv][(i + 2) * 4 + head], a3 = sa[wv][(i + 3) * 4 + head];
            float2 r0 = *(const float2*)&h1[(size_t)s0 * 256 + lane * 4];
            float2 r1 = *(const float2*)&h1[(size_t)s1 * 256 + lane * 4];
            float2 r2 = *(const float2*)&h1[(size_t)s2 * 256 + lane * 4];
            float2 r3 = *(const float2*)&h1[(size_t)s3 * 256 + lane * 4];
            fma4(a0, h4_to_f4(r0), acc);
            fma4(a1, h4_to_f4(r1), acc);
            fma4(a2, h4_to_f4(r2), acc);
            fma4(a3, h4_to_f4(r3), acc);
        }
        for (; i < cnt; ++i) {
            int s0 = ss[wv][i];
            float a0 = sa[wv][i * 4 + head];
            float2 r0 = *(const float2*)&h1[(size_t)s0 * 256 + lane * 4];
            fma4(a0, h4_to_f4(r0), acc);
        }
    }

#pragma unroll
    for (int off = 1; off < 64; off <<= 1) {
        asum.x += __shfl_xor(asum.x, off);
        asum.y += __shfl_xor(asum.y, off);
        asum.z += __shfl_xor(asum.z, off);
        asum.w += __shfl_xor(asum.w, off);
    }
    float ssum = (head == 0) ? asum.x : (head == 1) ? asum.y : (head == 2) ? asum.z : asum.w;
    float inv = 1.f / (ssum + 1e-16f);
    float4 bb = *(const float4*)&b1[lane * 4];
    float4 v;
    v.x = acc.x * inv + bb.x; v.y = acc.y * inv + bb.y;
    v.z = acc.z * inv + bb.z; v.w = acc.w * inv + bb.w;
    v.x = (v.x > 0.f) ? v.x : (__expf(v.x) - 1.f);
    v.y = (v.y > 0.f) ? v.y : (__expf(v.y) - 1.f);
    v.z = (v.z > 0.f) ? v.z : (__expf(v.z) - 1.f);
    v.w = (v.w > 0.f) ? v.w : (__expf(v.w) - 1.f);
    *(float4*)&y1[(size_t)n * 256 + lane * 4] = v;
}

// ---------------- GEMM2: h2 = y1 @ W2  [M,256]@[256,32], fp16 out, fused att dots ----------------

__global__ __launch_bounds__(256) void k_gemm2(const float* __restrict__ y1,
                                               const float* __restrict__ W,
                                               const float* __restrict__ att_src,
                                               const float* __restrict__ att_dst,
                                               __half* __restrict__ h2,
                                               float* __restrict__ a_s,
                                               float* __restrict__ a_d, int M) {
    __shared__ float xs[256][32];
    __shared__ float ws2[256 * 32];
    int tid = threadIdx.x;
    int row0 = blockIdx.x * 32;
    for (int t = tid; t < 2048; t += 256) {
        int k4 = t >> 5, m = t & 31;
        int r = row0 + m;
        float4 v = make_float4(0.f, 0.f, 0.f, 0.f);
        if (r < M) v = *(const float4*)&y1[(size_t)r * 256 + k4 * 4];
        xs[k4 * 4 + 0][m] = v.x;
        xs[k4 * 4 + 1][m] = v.y;
        xs[k4 * 4 + 2][m] = v.z;
        xs[k4 * 4 + 3][m] = v.w;
    }
    for (int t = tid; t < 2048; t += 256)
        *(float4*)&ws2[t * 4] = *(const float4*)&W[t * 4];
    __syncthreads();

    int tx = tid & 7, ty = tid >> 3;
    float acc[4] = {};
#pragma unroll 4
    for (int k = 0; k < 256; ++k) {
        float a = xs[k][ty];
        float4 b = *(const float4*)&ws2[k * 32 + tx * 4];
        acc[0] += a * b.x; acc[1] += a * b.y; acc[2] += a * b.z; acc[3] += a * b.w;
    }
    int r = row0 + ty;
    if (r < M) {
        __half2 p01 = __floats2half2_rn(acc[0], acc[1]);
        __half2 p23 = __floats2half2_rn(acc[2], acc[3]);
        float2 st;
        *(__half2*)&st.x = p01;
        *(__half2*)&st.y = p23;
        *(float2*)&h2[(size_t)r * 32 + tx * 4] = st;
    }

    float s_ = 0.f, d_ = 0.f;
#pragma unroll
    for (int j = 0; j < 4; ++j) {
        s_ = fmaf(acc[j], att_src[tx * 4 + j], s_);
        d_ = fmaf(acc[j], att_dst[tx * 4 + j], d_);
    }
#pragma unroll
    for (int off = 1; off < 8; off <<= 1) {
        s_ += __shfl_xor(s_, off);
        d_ += __shfl_xor(d_, off);
    }
    if (tx == 0 && r < M) { a_s[r] = s_; a_d[r] = d_; }
}

// ---------------- alpha layer 2 ----------------

__global__ __launch_bounds__(256) void k_alpha2(const float* __restrict__ asrc,
                                                const float* __restrict__ adst,
                                                const int* __restrict__ row_ptr,
                                                const int* __restrict__ esrc,
                                                float* __restrict__ alpha, int N) {
    int g = threadIdx.x >> 5, c = threadIdx.x & 31;
    int n = blockIdx.x * 8 + g;
    if (n >= N) return;
    int e0 = row_ptr[n], e1 = row_ptr[n + 1];
    int deg = e1 - e0;
    if (deg == 0) return;
    float ad = adst[n];
    if (deg <= 32) {
        float l = -3e38f;
        if (c < deg) l = lrelu(asrc[esrc[e0 + c]] + ad);
        float m = l;
#pragma unroll
        for (int off = 16; off; off >>= 1) m = fmaxf(m, __shfl_xor(m, off, 32));
        if (c < deg) alpha[e0 + c] = __expf(l - m);
    } else {
        float m = -3e38f;
        for (int p0 = e0; p0 < e1; p0 += 32) {
            int e = p0 + c;
            if (e < e1) m = fmaxf(m, lrelu(asrc[esrc[e]] + ad));
        }
#pragma unroll
        for (int off = 16; off; off >>= 1) m = fmaxf(m, __shfl_xor(m, off, 32));
        for (int p0 = e0; p0 < e1; p0 += 32) {
            int e = p0 + c;
            if (e < e1) alpha[e] = __expf(lrelu(asrc[esrc[e]] + ad) - m);
        }
    }
}

// ---------------- agg layer 2: wave-per-node, fp16 gather, 4 edges x 16 lanes ----------------

__global__ __launch_bounds__(256) void k_agg2(const __half* __restrict__ h2,
                                              const int* __restrict__ row_ptr,
                                              const int* __restrict__ esrc,
                                              const float* __restrict__ alpha,
                                              const float* __restrict__ b2,
                                              float* __restrict__ out, int N) {
    __shared__ int ss[4][64];
    __shared__ float sa[4][64];
    int tid = threadIdx.x;
    int wv = tid >> 6, lane = tid & 63;
    int n = blockIdx.x * 4 + wv;
    if (n >= N) return;
    int grp = lane >> 4, cl = lane & 15;   // edge group, channel pair index
    int e0 = row_ptr[n], e1 = row_ptr[n + 1];
    float2 acc = make_float2(0.f, 0.f);
    float asum = 0.f;

    for (int p0 = e0; p0 < e1; p0 += 64) {
        int cnt = min(64, e1 - p0);
        if (lane < cnt) {
            ss[wv][lane] = esrc[p0 + lane];
            float a = alpha[p0 + lane];
            sa[wv][lane] = a;
            asum += a;
        }
        int i = 0;
        for (; i + 7 < cnt; i += 8) {
            int ea = i + grp, eb = i + 4 + grp;
            int s0 = ss[wv][ea], s1 = ss[wv][eb];
            float a0 = sa[wv][ea], a1 = sa[wv][eb];
            __half2 v0 = *(const __half2*)&h2[(size_t)s0 * 32 + cl * 2];
            __half2 v1 = *(const __half2*)&h2[(size_t)s1 * 32 + cl * 2];
            float2 f0 = __half22float2(v0), f1 = __half22float2(v1);
            acc.x = fmaf(a0, f0.x, acc.x); acc.y = fmaf(a0, f0.y, acc.y);
            acc.x = fmaf(a1, f1.x, acc.x); acc.y = fmaf(a1, f1.y, acc.y);
        }
        for (; i < cnt; i += 4) {
            int e = i + grp;
            if (e < cnt) {
                int s0 = ss[wv][e];
                float a0 = sa[wv][e];
                __half2 v0 = *(const __half2*)&h2[(size_t)s0 * 32 + cl * 2];
                float2 f0 = __half22float2(v0);
                acc.x = fmaf(a0, f0.x, acc.x); acc.y = fmaf(a0, f0.y, acc.y);
            }
        }
    }
    // sum partial edge-group accumulators (groups differ in lane bits 4,5)
    acc.x += __shfl_xor(acc.x, 16); acc.y += __shfl_xor(acc.y, 16);
    acc.x += __shfl_xor(acc.x, 32); acc.y += __shfl_xor(acc.y, 32);
#pragma unroll
    for (int off = 1; off < 64; off <<= 1) asum += __shfl_xor(asum, off);
    if (grp == 0) {
        float inv = 1.f / (asum + 1e-16f);
        float2 o;
        o.x = acc.x * inv + b2[cl * 2];
        o.y = acc.y * inv + b2[cl * 2 + 1];
        *(float2*)&out[(size_t)n * 32 + cl * 2] = o;
    }
}

// ---------------- launcher ----------------

extern "C" void kernel_launch(void* const* d_in, const int* in_sizes, int n_in,
                              void* d_out, int out_size, void* d_ws, size_t ws_size,
                              hipStream_t stream) {
    const float* x   = (const float*)d_in[0];
    const int*   ei  = (const int*)d_in[1];
    const float* W1  = (const float*)d_in[2];
    const float* as1 = (const float*)d_in[3];
    const float* ad1 = (const float*)d_in[4];
    const float* b1  = (const float*)d_in[5];
    const float* W2  = (const float*)d_in[6];
    const float* as2 = (const float*)d_in[7];
    const float* ad2 = (const float*)d_in[8];
    const float* b2  = (const float*)d_in[9];
    float* out = (float*)d_out;

    const int N = in_sizes[0] / 128;   // 50000
    const int E = in_sizes[1] / 2;     // 800000
    const int* src = ei;
    const int* dstp = ei + E;
    const int nb = (N + 1023) / 1024;

    char* ws = (char*)d_ws;
    size_t off = 0;
    auto alloc = [&](size_t nbytes) {
        void* p = ws + off;
        off += (nbytes + 255) & ~(size_t)255;
        return p;
    };
    int* counts    = (int*)alloc((size_t)N * 4);
    int* row_ptr   = (int*)alloc((size_t)(N + 1) * 4);
    int* row_fill  = (int*)alloc((size_t)N * 4);
    int* esrc      = (int*)alloc((size_t)E * 4);
    __half* h1     = (__half*)alloc((size_t)N * 256 * 2);
    float* y1      = (float*)alloc((size_t)N * 256 * 4);
    __half* h2     = (__half*)alloc((size_t)N * 32 * 2);
    float* a_s1    = (float*)alloc((size_t)N * 4 * 4);
    float* a_d1    = (float*)alloc((size_t)N * 4 * 4);
    float* a_s2    = (float*)alloc((size_t)N * 4);
    float* a_d2    = (float*)alloc((size_t)N * 4);
    float* alpha1  = (float*)alloc((size_t)E * 4 * 4);
    float* alpha2  = (float*)alloc((size_t)E * 4);
    int* bsum      = (int*)alloc((size_t)nb * 4);
    int* boff      = (int*)alloc((size_t)nb * 4);
    __half* Wt     = (__half*)alloc((size_t)256 * 128 * 2);

    hipMemsetAsync(counts, 0, (size_t)N * 4, stream);
    k_hist<<<(E + 255) / 256, 256, 0, stream>>>(dstp, counts, E);
    k_scan1<<<nb, 256, 0, stream>>>(counts, bsum, N);
    k_scan2<<<1, 64, 0, stream>>>(bsum, boff, &row_ptr[N], nb);
    k_scan3<<<nb, 256, 0, stream>>>(counts, boff, row_ptr, row_fill, N);
    k_scatter<<<(E + 255) / 256, 256, 0, stream>>>(src, dstp, row_fill, esrc, E);

    k_w1t<<<256, 128, 0, stream>>>(W1, Wt);
    k_gemm1<<<dim3((N + 63) / 64, 2), 256, 0, stream>>>(x, Wt, as1, ad1, h1, a_s1, a_d1, N);
    k_alpha1<<<(N + 3) / 4, 256, 0, stream>>>(a_s1, a_d1, row_ptr, esrc, alpha1, N);
    k_agg1<<<(N + 3) / 4, 256, 0, stream>>>(h1, row_ptr, esrc, alpha1, b1, y1, N);

    k_gemm2<<<(N + 31) / 32, 256, 0, stream>>>(y1, W2, as2, ad2, h2, a_s2, a_d2, N);
    k_alpha2<<<(N + 7) / 8, 256, 0, stream>>>(a_s2, a_d2, row_ptr, esrc, alpha2, N);
    k_agg2<<<(N + 3) / 4, 256, 0, stream>>>(h2, row_ptr, esrc, alpha2, b2, out, N);
}

// Round 9
// 220.550 us; speedup vs baseline: 2.5649x; 1.2117x over previous
//
#include <hip/hip_runtime.h>
#include <hip/hip_bf16.h>
#include <hip/hip_fp16.h>

#define NEG_SLOPE 0.2f

typedef _Float16 half8 __attribute__((ext_vector_type(8)));
typedef float f32x4 __attribute__((ext_vector_type(4)));

__device__ __forceinline__ float lrelu(float x) { return x >= 0.f ? x : NEG_SLOPE * x; }

__device__ __forceinline__ float4 h4_to_f4(float2 r) {
    __half2 a = *(__half2*)&r.x;
    __half2 b = *(__half2*)&r.y;
    float2 fa = __half22float2(a), fb = __half22float2(b);
    return make_float4(fa.x, fa.y, fb.x, fb.y);
}

__device__ __forceinline__ void fma4(float a, float4 v, float4& acc) {
    acc.x = fmaf(a, v.x, acc.x); acc.y = fmaf(a, v.y, acc.y);
    acc.z = fmaf(a, v.z, acc.z); acc.w = fmaf(a, v.w, acc.w);
}

// ---------------- CSR construction ----------------

__global__ void k_hist(const int* __restrict__ dst, int* __restrict__ counts, int E) {
    int e = blockIdx.x * 256 + threadIdx.x;
    if (e < E) atomicAdd(&counts[dst[e]], 1);
}

__global__ __launch_bounds__(256) void k_scan1(const int* __restrict__ counts,
                                               int* __restrict__ bsum, int N) {
    __shared__ int wsum[4];
    int b = blockIdx.x, t = threadIdx.x;
    int i0 = b * 1024 + t * 4;
    int s = 0;
    if (i0 < N) { int4 v = *(const int4*)&counts[i0]; s = v.x + v.y + v.z + v.w; }
#pragma unroll
    for (int off = 32; off; off >>= 1) s += __shfl_down(s, off);
    if ((t & 63) == 0) wsum[t >> 6] = s;
    __syncthreads();
    if (t == 0) bsum[b] = wsum[0] + wsum[1] + wsum[2] + wsum[3];
}

__global__ void k_scan2(const int* __restrict__ bsum, int* __restrict__ boff,
                        int* __restrict__ row_ptrN, int nb) {
    int t = threadIdx.x;  // 64 threads, nb <= 64
    int v = (t < nb) ? bsum[t] : 0;
    int incl = v;
#pragma unroll
    for (int off = 1; off < 64; off <<= 1) {
        int u = __shfl_up(incl, off);
        if (t >= off) incl += u;
    }
    if (t < nb) boff[t] = incl - v;
    if (t == nb - 1) *row_ptrN = incl;
}

__global__ __launch_bounds__(256) void k_scan3(const int* __restrict__ counts,
                                               const int* __restrict__ boff,
                                               int* __restrict__ row_ptr,
                                               int* __restrict__ row_fill, int N) {
    __shared__ int lds[256];
    int b = blockIdx.x, t = threadIdx.x;
    int i0 = b * 1024 + t * 4;
    int4 v = make_int4(0, 0, 0, 0);
    if (i0 < N) v = *(const int4*)&counts[i0];
    int tot = v.x + v.y + v.z + v.w;
    lds[t] = tot;
    __syncthreads();
    for (int off = 1; off < 256; off <<= 1) {
        int u = (t >= off) ? lds[t - off] : 0;
        __syncthreads();
        lds[t] += u;
        __syncthreads();
    }
    int excl = lds[t] - tot;
    int run = boff[b] + excl;
    if (i0 < N) {
        row_ptr[i0] = run;     row_fill[i0] = run;     run += v.x;
        row_ptr[i0 + 1] = run; row_fill[i0 + 1] = run; run += v.y;
        row_ptr[i0 + 2] = run; row_fill[i0 + 2] = run; run += v.z;
        row_ptr[i0 + 3] = run; row_fill[i0 + 3] = run;
    }
}

__global__ void k_scatter(const int* __restrict__ src, const int* __restrict__ dst,
                          int* __restrict__ row_fill, int* __restrict__ esrc, int E) {
    int e = blockIdx.x * 256 + threadIdx.x;
    if (e < E) {
        int p = atomicAdd(&row_fill[dst[e]], 1);
        esrc[p] = src[e];
    }
}

// ---------------- weight transposes to fp16 ----------------

__global__ __launch_bounds__(128) void k_w1t(const float* __restrict__ W,
                                             __half* __restrict__ Wt) {
    int n = blockIdx.x;       // 256
    int k = threadIdx.x;      // 128
    Wt[n * 128 + k] = __float2half(W[(size_t)k * 256 + n]);
}

__global__ __launch_bounds__(256) void k_w2t(const float* __restrict__ W,
                                             __half* __restrict__ Wt) {
    int n = blockIdx.x;       // 32
    int k = threadIdx.x;      // 256
    Wt[n * 256 + k] = __float2half(W[(size_t)k * 32 + n]);
}

// ---------------- GEMM1 (MFMA fp16): h1 = x @ W1, fused att dots ----------------

__global__ __launch_bounds__(256, 3) void k_gemm1(const float* __restrict__ x,
                                                  const __half* __restrict__ Wt,
                                                  const float* __restrict__ att_src,
                                                  const float* __restrict__ att_dst,
                                                  __half* __restrict__ h,
                                                  float* __restrict__ a_s,
                                                  float* __restrict__ a_d, int M) {
    __shared__ __align__(16) __half Xs[64 * 128];    // [row][k], XOR-swizzled 16B chunks
    __shared__ __align__(16) __half Ws[128 * 128];   // [n][k], XOR-swizzled 16B chunks
    const int tid = threadIdx.x;
    const int row0 = blockIdx.x * 64;
    const int by = blockIdx.y;            // 0..1 -> cols by*128..by*128+127
    const int col0 = by * 128;

    for (int t = 0; t < 4; ++t) {
        int c = tid + t * 256;            // 0..1023
        int row = c >> 4, ch = c & 15;
        int r = row0 + row;
        float4 va = make_float4(0.f, 0.f, 0.f, 0.f), vb = va;
        if (r < M) {
            va = *(const float4*)&x[(size_t)r * 128 + ch * 8];
            vb = *(const float4*)&x[(size_t)r * 128 + ch * 8 + 4];
        }
        half8 hv;
        hv[0] = (_Float16)va.x; hv[1] = (_Float16)va.y;
        hv[2] = (_Float16)va.z; hv[3] = (_Float16)va.w;
        hv[4] = (_Float16)vb.x; hv[5] = (_Float16)vb.y;
        hv[6] = (_Float16)vb.z; hv[7] = (_Float16)vb.w;
        *(half8*)((char*)Xs + row * 256 + ((ch * 16) ^ ((row & 7) << 4))) = hv;
    }
    for (int t = 0; t < 8; ++t) {
        int c = tid + t * 256;            // 0..2047
        int n = c >> 4, ch = c & 15;
        float4 v = *(const float4*)&Wt[(size_t)(col0 + n) * 128 + ch * 8];
        *(float4*)((char*)Ws + n * 256 + ((ch * 16) ^ ((n & 7) << 4))) = v;
    }
    __syncthreads();

    const int w = tid >> 6, lane = tid & 63;
    const int col_l = lane & 15, kgrp = lane >> 4;
    const int arow = w * 16 + col_l;
    const int sw = (col_l & 7) << 4;

    f32x4 acc[8];
#pragma unroll
    for (int nt = 0; nt < 8; ++nt) acc[nt] = (f32x4){0.f, 0.f, 0.f, 0.f};

#pragma unroll
    for (int ks = 0; ks < 4; ++ks) {
        int kchunk = (ks * 4 + kgrp) * 16;
        half8 av = *(const half8*)((const char*)Xs + arow * 256 + (kchunk ^ sw));
#pragma unroll
        for (int nt = 0; nt < 8; ++nt) {
            half8 bv = *(const half8*)((const char*)Ws + (nt * 16 + col_l) * 256 + (kchunk ^ sw));
            acc[nt] = __builtin_amdgcn_mfma_f32_16x16x32_f16(av, bv, acc[nt], 0, 0, 0);
        }
    }

    float asv[8], adv[8];
#pragma unroll
    for (int nt = 0; nt < 8; ++nt) {
        int gc = col0 + nt * 16 + col_l;
        asv[nt] = att_src[gc];
        adv[nt] = att_dst[gc];
    }
    const int rbase = row0 + w * 16 + kgrp * 4;
#pragma unroll
    for (int reg = 0; reg < 4; ++reg) {
        int gr = rbase + reg;
        if (gr < M) {
#pragma unroll
            for (int nt = 0; nt < 8; ++nt)
                h[(size_t)gr * 256 + col0 + nt * 16 + col_l] = __float2half(acc[nt][reg]);
        }
        float s0 = 0.f, d0 = 0.f, s1 = 0.f, d1 = 0.f;
#pragma unroll
        for (int nt = 0; nt < 4; ++nt) {
            s0 = fmaf(acc[nt][reg], asv[nt], s0);
            d0 = fmaf(acc[nt][reg], adv[nt], d0);
            s1 = fmaf(acc[nt + 4][reg], asv[nt + 4], s1);
            d1 = fmaf(acc[nt + 4][reg], adv[nt + 4], d1);
        }
#pragma unroll
        for (int off = 1; off < 16; off <<= 1) {
            s0 += __shfl_xor(s0, off); d0 += __shfl_xor(d0, off);
            s1 += __shfl_xor(s1, off); d1 += __shfl_xor(d1, off);
        }
        if (col_l == 0 && gr < M) {
            a_s[(size_t)gr * 4 + by * 2]     = s0;
            a_s[(size_t)gr * 4 + by * 2 + 1] = s1;
            a_d[(size_t)gr * 4 + by * 2]     = d0;
            a_d[(size_t)gr * 4 + by * 2 + 1] = d1;
        }
    }
}

// ---------------- agg layer 1 (fused softmax): wave-per-node ----------------

__global__ __launch_bounds__(256) void k_agg1(const __half* __restrict__ h1,
                                              const int* __restrict__ row_ptr,
                                              const int* __restrict__ esrc,
                                              const float* __restrict__ asrc,
                                              const float* __restrict__ adst,
                                              const float* __restrict__ b1,
                                              __half* __restrict__ y1, int N) {
    __shared__ int ss[4][64];
    __shared__ float sa[4][64 * 4];
    int tid = threadIdx.x;
    int wv = tid >> 6, lane = tid & 63;
    int n = blockIdx.x * 4 + wv;
    if (n >= N) return;
    int head = lane >> 4;
    int e0 = row_ptr[n], e1 = row_ptr[n + 1];
    int deg = e1 - e0;
    const float4 ad = *(const float4*)&adst[(size_t)n * 4];
    float4 acc = make_float4(0.f, 0.f, 0.f, 0.f);
    float4 asum = make_float4(0.f, 0.f, 0.f, 0.f);

    if (deg <= 64) {
        float4 l = make_float4(-3e38f, -3e38f, -3e38f, -3e38f);
        if (lane < deg) {
            int s = esrc[e0 + lane];
            ss[wv][lane] = s;
            float4 as = *(const float4*)&asrc[(size_t)s * 4];
            l.x = lrelu(as.x + ad.x); l.y = lrelu(as.y + ad.y);
            l.z = lrelu(as.z + ad.z); l.w = lrelu(as.w + ad.w);
        }
        float4 m = l;
#pragma unroll
        for (int off = 1; off < 64; off <<= 1) {
            m.x = fmaxf(m.x, __shfl_xor(m.x, off));
            m.y = fmaxf(m.y, __shfl_xor(m.y, off));
            m.z = fmaxf(m.z, __shfl_xor(m.z, off));
            m.w = fmaxf(m.w, __shfl_xor(m.w, off));
        }
        float4 a = make_float4(0.f, 0.f, 0.f, 0.f);
        if (lane < deg) {
            a.x = __expf(l.x - m.x); a.y = __expf(l.y - m.y);
            a.z = __expf(l.z - m.z); a.w = __expf(l.w - m.w);
            *(float4*)&sa[wv][lane * 4] = a;
        }
        asum = a;
        int i = 0;
        for (; i + 3 < deg; i += 4) {
            int s0 = ss[wv][i], s1 = ss[wv][i + 1], s2 = ss[wv][i + 2], s3 = ss[wv][i + 3];
            float a0 = sa[wv][i * 4 + head],       a1 = sa[wv][(i + 1) * 4 + head];
            float a2 = sa[wv][(i + 2) * 4 + head], a3 = sa[wv][(i + 3) * 4 + head];
            float2 r0 = *(const float2*)&h1[(size_t)s0 * 256 + lane * 4];
            float2 r1 = *(const float2*)&h1[(size_t)s1 * 256 + lane * 4];
            float2 r2 = *(const float2*)&h1[(size_t)s2 * 256 + lane * 4];
            float2 r3 = *(const float2*)&h1[(size_t)s3 * 256 + lane * 4];
            fma4(a0, h4_to_f4(r0), acc);
            fma4(a1, h4_to_f4(r1), acc);
            fma4(a2, h4_to_f4(r2), acc);
            fma4(a3, h4_to_f4(r3), acc);
        }
        for (; i < deg; ++i) {
            int s0 = ss[wv][i];
            float a0 = sa[wv][i * 4 + head];
            float2 r0 = *(const float2*)&h1[(size_t)s0 * 256 + lane * 4];
            fma4(a0, h4_to_f4(r0), acc);
        }
    } else {
        float4 m = make_float4(-3e38f, -3e38f, -3e38f, -3e38f);
        for (int p0 = e0; p0 < e1; p0 += 64) {
            int e = p0 + lane;
            if (e < e1) {
                int s = esrc[e];
                float4 as = *(const float4*)&asrc[(size_t)s * 4];
                m.x = fmaxf(m.x, lrelu(as.x + ad.x));
                m.y = fmaxf(m.y, lrelu(as.y + ad.y));
                m.z = fmaxf(m.z, lrelu(as.z + ad.z));
                m.w = fmaxf(m.w, lrelu(as.w + ad.w));
            }
        }
#pragma unroll
        for (int off = 1; off < 64; off <<= 1) {
            m.x = fmaxf(m.x, __shfl_xor(m.x, off));
            m.y = fmaxf(m.y, __shfl_xor(m.y, off));
            m.z = fmaxf(m.z, __shfl_xor(m.z, off));
            m.w = fmaxf(m.w, __shfl_xor(m.w, off));
        }
        for (int p0 = e0; p0 < e1; p0 += 64) {
            int cnt = min(64, e1 - p0);
            if (lane < cnt) {
                int s = esrc[p0 + lane];
                ss[wv][lane] = s;
                float4 as = *(const float4*)&asrc[(size_t)s * 4];
                float4 a;
                a.x = __expf(lrelu(as.x + ad.x) - m.x);
                a.y = __expf(lrelu(as.y + ad.y) - m.y);
                a.z = __expf(lrelu(as.z + ad.z) - m.z);
                a.w = __expf(lrelu(as.w + ad.w) - m.w);
                *(float4*)&sa[wv][lane * 4] = a;
                asum.x += a.x; asum.y += a.y; asum.z += a.z; asum.w += a.w;
            }
            int i = 0;
            for (; i + 3 < cnt; i += 4) {
                int s0 = ss[wv][i], s1 = ss[wv][i + 1], s2 = ss[wv][i + 2], s3 = ss[wv][i + 3];
                float a0 = sa[wv][i * 4 + head],       a1 = sa[wv][(i + 1) * 4 + head];
                float a2 = sa[wv][(i + 2) * 4 + head], a3 = sa[wv][(i + 3) * 4 + head];
                float2 r0 = *(const float2*)&h1[(size_t)s0 * 256 + lane * 4];
                float2 r1 = *(const float2*)&h1[(size_t)s1 * 256 + lane * 4];
                float2 r2 = *(const float2*)&h1[(size_t)s2 * 256 + lane * 4];
                float2 r3 = *(const float2*)&h1[(size_t)s3 * 256 + lane * 4];
                fma4(a0, h4_to_f4(r0), acc);
                fma4(a1, h4_to_f4(r1), acc);
                fma4(a2, h4_to_f4(r2), acc);
                fma4(a3, h4_to_f4(r3), acc);
            }
            for (; i < cnt; ++i) {
                int s0 = ss[wv][i];
                float a0 = sa[wv][i * 4 + head];
                float2 r0 = *(const float2*)&h1[(size_t)s0 * 256 + lane * 4];
                fma4(a0, h4_to_f4(r0), acc);
            }
        }
    }

#pragma unroll
    for (int off = 1; off < 64; off <<= 1) {
        asum.x += __shfl_xor(asum.x, off);
        asum.y += __shfl_xor(asum.y, off);
        asum.z += __shfl_xor(asum.z, off);
        asum.w += __shfl_xor(asum.w, off);
    }
    float ssum = (head == 0) ? asum.x : (head == 1) ? asum.y : (head == 2) ? asum.z : asum.w;
    float inv = 1.f / (ssum + 1e-16f);
    float4 bb = *(const float4*)&b1[lane * 4];
    float4 v;
    v.x = acc.x * inv + bb.x; v.y = acc.y * inv + bb.y;
    v.z = acc.z * inv + bb.z; v.w = acc.w * inv + bb.w;
    v.x = (v.x > 0.f) ? v.x : (__expf(v.x) - 1.f);
    v.y = (v.y > 0.f) ? v.y : (__expf(v.y) - 1.f);
    v.z = (v.z > 0.f) ? v.z : (__expf(v.z) - 1.f);
    v.w = (v.w > 0.f) ? v.w : (__expf(v.w) - 1.f);
    __half2 h01 = __floats2half2_rn(v.x, v.y);
    __half2 h23 = __floats2half2_rn(v.z, v.w);
    float2 st;
    *(__half2*)&st.x = h01;
    *(__half2*)&st.y = h23;
    *(float2*)&y1[(size_t)n * 256 + lane * 4] = st;
}

// ---------------- GEMM2 (MFMA fp16): h2 = y1 @ W2, fused att dots ----------------

__global__ __launch_bounds__(256, 3) void k_gemm2(const __half* __restrict__ y1,
                                                  const __half* __restrict__ W2t,
                                                  const float* __restrict__ att_src,
                                                  const float* __restrict__ att_dst,
                                                  __half* __restrict__ h2,
                                                  float* __restrict__ a_s,
                                                  float* __restrict__ a_d, int M) {
    __shared__ __align__(16) __half Ys[64 * 256];    // 32KB, swizzled
    __shared__ __align__(16) __half Ws[32 * 256];    // 16KB, swizzled
    const int tid = threadIdx.x;
    const int row0 = blockIdx.x * 64;

    for (int t = 0; t < 8; ++t) {
        int c = tid + t * 256;            // 0..2047
        int row = c >> 5, ch = c & 31;
        int r = row0 + row;
        float4 v = make_float4(0.f, 0.f, 0.f, 0.f);
        if (r < M) v = *(const float4*)&y1[(size_t)r * 256 + ch * 8];
        *(float4*)((char*)Ys + row * 512 + ((ch * 16) ^ ((row & 7) << 4))) = v;
    }
    for (int t = 0; t < 4; ++t) {
        int c = tid + t * 256;            // 0..1023
        int n = c >> 5, ch = c & 31;
        float4 v = *(const float4*)&W2t[(size_t)n * 256 + ch * 8];
        *(float4*)((char*)Ws + n * 512 + ((ch * 16) ^ ((n & 7) << 4))) = v;
    }
    __syncthreads();

    const int w = tid >> 6, lane = tid & 63;
    const int col_l = lane & 15, kgrp = lane >> 4;
    const int arow = w * 16 + col_l;
    const int sw = (col_l & 7) << 4;

    f32x4 acc[2];
    acc[0] = (f32x4){0.f, 0.f, 0.f, 0.f};
    acc[1] = (f32x4){0.f, 0.f, 0.f, 0.f};

#pragma unroll
    for (int ks = 0; ks < 8; ++ks) {
        int kchunk = (ks * 4 + kgrp) * 16;
        half8 av = *(const half8*)((const char*)Ys + arow * 512 + (kchunk ^ sw));
#pragma unroll
        for (int nt = 0; nt < 2; ++nt) {
            half8 bv = *(const half8*)((const char*)Ws + (nt * 16 + col_l) * 512 + (kchunk ^ sw));
            acc[nt] = __builtin_amdgcn_mfma_f32_16x16x32_f16(av, bv, acc[nt], 0, 0, 0);
        }
    }

    float asv[2], adv[2];
#pragma unroll
    for (int nt = 0; nt < 2; ++nt) {
        asv[nt] = att_src[nt * 16 + col_l];
        adv[nt] = att_dst[nt * 16 + col_l];
    }
    const int rbase = row0 + w * 16 + kgrp * 4;
#pragma unroll
    for (int reg = 0; reg < 4; ++reg) {
        int gr = rbase + reg;
        if (gr < M) {
            h2[(size_t)gr * 32 + col_l]      = __float2half(acc[0][reg]);
            h2[(size_t)gr * 32 + 16 + col_l] = __float2half(acc[1][reg]);
        }
        float s_ = fmaf(acc[0][reg], asv[0], acc[1][reg] * asv[1]);
        float d_ = fmaf(acc[0][reg], adv[0], acc[1][reg] * adv[1]);
#pragma unroll
        for (int off = 1; off < 16; off <<= 1) {
            s_ += __shfl_xor(s_, off);
            d_ += __shfl_xor(d_, off);
        }
        if (col_l == 0 && gr < M) { a_s[gr] = s_; a_d[gr] = d_; }
    }
}

// ---------------- agg layer 2 (fused softmax): wave-per-node ----------------

__global__ __launch_bounds__(256) void k_agg2(const __half* __restrict__ h2,
                                              const int* __restrict__ row_ptr,
                                              const int* __restrict__ esrc,
                                              const float* __restrict__ asrc,
                                              const float* __restrict__ adst,
                                              const float* __restrict__ b2,
                                              float* __restrict__ out, int N) {
    __shared__ int ss[4][64];
    __shared__ float sa[4][64];
    int tid = threadIdx.x;
    int wv = tid >> 6, lane = tid & 63;
    int n = blockIdx.x * 4 + wv;
    if (n >= N) return;
    int grp = lane >> 4, cl = lane & 15;
    int e0 = row_ptr[n], e1 = row_ptr[n + 1];
    int deg = e1 - e0;
    float ad = adst[n];
    float2 acc = make_float2(0.f, 0.f);
    float asum = 0.f;

    auto gather = [&](int cnt) {
        int i = 0;
        for (; i + 7 < cnt; i += 8) {
            int ea = i + grp, eb = i + 4 + grp;
            int s0 = ss[wv][ea], s1 = ss[wv][eb];
            float a0 = sa[wv][ea], a1 = sa[wv][eb];
            __half2 v0 = *(const __half2*)&h2[(size_t)s0 * 32 + cl * 2];
            __half2 v1 = *(const __half2*)&h2[(size_t)s1 * 32 + cl * 2];
            float2 f0 = __half22float2(v0), f1 = __half22float2(v1);
            acc.x = fmaf(a0, f0.x, acc.x); acc.y = fmaf(a0, f0.y, acc.y);
            acc.x = fmaf(a1, f1.x, acc.x); acc.y = fmaf(a1, f1.y, acc.y);
        }
        for (; i < cnt; i += 4) {
            int e = i + grp;
            if (e < cnt) {
                int s0 = ss[wv][e];
                float a0 = sa[wv][e];
                __half2 v0 = *(const __half2*)&h2[(size_t)s0 * 32 + cl * 2];
                float2 f0 = __half22float2(v0);
                acc.x = fmaf(a0, f0.x, acc.x); acc.y = fmaf(a0, f0.y, acc.y);
            }
        }
    };

    if (deg <= 64) {
        float l = -3e38f;
        if (lane < deg) {
            int s = esrc[e0 + lane];
            ss[wv][lane] = s;
            l = lrelu(asrc[s] + ad);
        }
        float m = l;
#pragma unroll
        for (int off = 1; off < 64; off <<= 1) m = fmaxf(m, __shfl_xor(m, off));
        float a = 0.f;
        if (lane < deg) {
            a = __expf(l - m);
            sa[wv][lane] = a;
        }
        asum = a;
        gather(deg);
    } else {
        float m = -3e38f;
        for (int p0 = e0; p0 < e1; p0 += 64) {
            int e = p0 + lane;
            if (e < e1) m = fmaxf(m, lrelu(asrc[esrc[e]] + ad));
        }
#pragma unroll
        for (int off = 1; off < 64; off <<= 1) m = fmaxf(m, __shfl_xor(m, off));
        for (int p0 = e0; p0 < e1; p0 += 64) {
            int cnt = min(64, e1 - p0);
            if (lane < cnt) {
                int s = esrc[p0 + lane];
                ss[wv][lane] = s;
                float a = __expf(lrelu(asrc[s] + ad) - m);
                sa[wv][lane] = a;
                asum += a;
            }
            gather(cnt);
        }
    }

    acc.x += __shfl_xor(acc.x, 16); acc.y += __shfl_xor(acc.y, 16);
    acc.x += __shfl_xor(acc.x, 32); acc.y += __shfl_xor(acc.y, 32);
#pragma unroll
    for (int off = 1; off < 64; off <<= 1) asum += __shfl_xor(asum, off);
    if (grp == 0) {
        float inv = 1.f / (asum + 1e-16f);
        float2 o;
        o.x = acc.x * inv + b2[cl * 2];
        o.y = acc.y * inv + b2[cl * 2 + 1];
        *(float2*)&out[(size_t)n * 32 + cl * 2] = o;
    }
}

// ---------------- launcher ----------------

extern "C" void kernel_launch(void* const* d_in, const int* in_sizes, int n_in,
                              void* d_out, int out_size, void* d_ws, size_t ws_size,
                              hipStream_t stream) {
    const float* x   = (const float*)d_in[0];
    const int*   ei  = (const int*)d_in[1];
    const float* W1  = (const float*)d_in[2];
    const float* as1 = (const float*)d_in[3];
    const float* ad1 = (const float*)d_in[4];
    const float* b1  = (const float*)d_in[5];
    const float* W2  = (const float*)d_in[6];
    const float* as2 = (const float*)d_in[7];
    const float* ad2 = (const float*)d_in[8];
    const float* b2  = (const float*)d_in[9];
    float* out = (float*)d_out;

    const int N = in_sizes[0] / 128;   // 50000
    const int E = in_sizes[1] / 2;     // 800000
    const int* src = ei;
    const int* dstp = ei + E;
    const int nb = (N + 1023) / 1024;

    char* ws = (char*)d_ws;
    size_t off = 0;
    auto alloc = [&](size_t nbytes) {
        void* p = ws + off;
        off += (nbytes + 255) & ~(size_t)255;
        return p;
    };
    int* counts    = (int*)alloc((size_t)N * 4);
    int* row_ptr   = (int*)alloc((size_t)(N + 1) * 4);
    int* row_fill  = (int*)alloc((size_t)N * 4);
    int* esrc      = (int*)alloc((size_t)E * 4);
    __half* h1     = (__half*)alloc((size_t)N * 256 * 2);
    __half* y1     = (__half*)alloc((size_t)N * 256 * 2);
    __half* h2     = (__half*)alloc((size_t)N * 32 * 2);
    float* a_s1    = (float*)alloc((size_t)N * 4 * 4);
    float* a_d1    = (float*)alloc((size_t)N * 4 * 4);
    float* a_s2    = (float*)alloc((size_t)N * 4);
    float* a_d2    = (float*)alloc((size_t)N * 4);
    int* bsum      = (int*)alloc((size_t)nb * 4);
    int* boff      = (int*)alloc((size_t)nb * 4);
    __half* Wt     = (__half*)alloc((size_t)256 * 128 * 2);
    __half* W2t    = (__half*)alloc((size_t)32 * 256 * 2);

    hipMemsetAsync(counts, 0, (size_t)N * 4, stream);
    k_hist<<<(E + 255) / 256, 256, 0, stream>>>(dstp, counts, E);
    k_scan1<<<nb, 256, 0, stream>>>(counts, bsum, N);
    k_scan2<<<1, 64, 0, stream>>>(bsum, boff, &row_ptr[N], nb);
    k_scan3<<<nb, 256, 0, stream>>>(counts, boff, row_ptr, row_fill, N);
    k_scatter<<<(E + 255) / 256, 256, 0, stream>>>(src, dstp, row_fill, esrc, E);

    k_w1t<<<256, 128, 0, stream>>>(W1, Wt);
    k_w2t<<<32, 256, 0, stream>>>(W2, W2t);

    k_gemm1<<<dim3((N + 63) / 64, 2), 256, 0, stream>>>(x, Wt, as1, ad1, h1, a_s1, a_d1, N);
    k_agg1<<<(N + 3) / 4, 256, 0, stream>>>(h1, row_ptr, esrc, a_s1, a_d1, b1, y1, N);

    k_gemm2<<<(N + 63) / 64, 256, 0, stream>>>(y1, W2t, as2, ad2, h2, a_s2, a_d2, N);
    k_agg2<<<(N + 3) / 4, 256, 0, stream>>>(h2, row_ptr, esrc, a_s2, a_d2, b2, out, N);
}

// Round 10
// 216.986 us; speedup vs baseline: 2.6071x; 1.0164x over previous
//
#include <hip/hip_runtime.h>
#include <hip/hip_bf16.h>
#include <hip/hip_fp16.h>

#define NEG_SLOPE 0.2f

typedef _Float16 half8 __attribute__((ext_vector_type(8)));
typedef float f32x4 __attribute__((ext_vector_type(4)));

__device__ __forceinline__ float lrelu(float x) { return x >= 0.f ? x : NEG_SLOPE * x; }

__device__ __forceinline__ float4 h4_to_f4(float2 r) {
    __half2 a = *(__half2*)&r.x;
    __half2 b = *(__half2*)&r.y;
    float2 fa = __half22float2(a), fb = __half22float2(b);
    return make_float4(fa.x, fa.y, fb.x, fb.y);
}

__device__ __forceinline__ void fma4(float a, float4 v, float4& acc) {
    acc.x = fmaf(a, v.x, acc.x); acc.y = fmaf(a, v.y, acc.y);
    acc.z = fmaf(a, v.z, acc.z); acc.w = fmaf(a, v.w, acc.w);
}

// ---------------- CSR construction ----------------

__global__ void k_hist(const int* __restrict__ dst, int* __restrict__ counts, int E) {
    int e = blockIdx.x * 256 + threadIdx.x;
    if (e < E) atomicAdd(&counts[dst[e]], 1);
}

__global__ __launch_bounds__(256) void k_scan1(const int* __restrict__ counts,
                                               int* __restrict__ bsum, int N) {
    __shared__ int wsum[4];
    int b = blockIdx.x, t = threadIdx.x;
    int i0 = b * 1024 + t * 4;
    int s = 0;
    if (i0 < N) { int4 v = *(const int4*)&counts[i0]; s = v.x + v.y + v.z + v.w; }
#pragma unroll
    for (int off = 32; off; off >>= 1) s += __shfl_down(s, off);
    if ((t & 63) == 0) wsum[t >> 6] = s;
    __syncthreads();
    if (t == 0) bsum[b] = wsum[0] + wsum[1] + wsum[2] + wsum[3];
}

__global__ void k_scan2(const int* __restrict__ bsum, int* __restrict__ boff,
                        int* __restrict__ row_ptrN, int nb) {
    int t = threadIdx.x;  // 64 threads, nb <= 64
    int v = (t < nb) ? bsum[t] : 0;
    int incl = v;
#pragma unroll
    for (int off = 1; off < 64; off <<= 1) {
        int u = __shfl_up(incl, off);
        if (t >= off) incl += u;
    }
    if (t < nb) boff[t] = incl - v;
    if (t == nb - 1) *row_ptrN = incl;
}

__global__ __launch_bounds__(256) void k_scan3(const int* __restrict__ counts,
                                               const int* __restrict__ boff,
                                               int* __restrict__ row_ptr,
                                               int* __restrict__ row_fill, int N) {
    __shared__ int lds[256];
    int b = blockIdx.x, t = threadIdx.x;
    int i0 = b * 1024 + t * 4;
    int4 v = make_int4(0, 0, 0, 0);
    if (i0 < N) v = *(const int4*)&counts[i0];
    int tot = v.x + v.y + v.z + v.w;
    lds[t] = tot;
    __syncthreads();
    for (int off = 1; off < 256; off <<= 1) {
        int u = (t >= off) ? lds[t - off] : 0;
        __syncthreads();
        lds[t] += u;
        __syncthreads();
    }
    int excl = lds[t] - tot;
    int run = boff[b] + excl;
    if (i0 < N) {
        row_ptr[i0] = run;     row_fill[i0] = run;     run += v.x;
        row_ptr[i0 + 1] = run; row_fill[i0 + 1] = run; run += v.y;
        row_ptr[i0 + 2] = run; row_fill[i0 + 2] = run; run += v.z;
        row_ptr[i0 + 3] = run; row_fill[i0 + 3] = run;
    }
}

__global__ void k_scatter(const int* __restrict__ src, const int* __restrict__ dst,
                          int* __restrict__ row_fill, int* __restrict__ esrc, int E) {
    int e = blockIdx.x * 256 + threadIdx.x;
    if (e < E) {
        int p = atomicAdd(&row_fill[dst[e]], 1);
        esrc[p] = src[e];
    }
}

// ---------------- weight transposes to fp16 (merged) ----------------

__global__ __launch_bounds__(256) void k_wt(const float* __restrict__ W1,
                                            const float* __restrict__ W2,
                                            __half* __restrict__ W1t,
                                            __half* __restrict__ W2t) {
    int b = blockIdx.x, k = threadIdx.x;
    if (b < 256) {
        if (k < 128) W1t[b * 128 + k] = __float2half(W1[(size_t)k * 256 + b]);
    } else {
        int n = b - 256;   // 0..31
        W2t[n * 256 + k] = __float2half(W2[(size_t)k * 32 + n]);
    }
}

// ---------------- GEMM1 (MFMA fp16): h1 = x @ W1, fused att dots ----------------
// Column permutation: LDS B slot (n&7)*16+(n>>3) holds logical column n, so each
// lane's 8 n-tile outputs are 8 CONTIGUOUS columns -> 16B coalesced stores.

__global__ __launch_bounds__(256, 3) void k_gemm1(const float* __restrict__ x,
                                                  const __half* __restrict__ Wt,
                                                  const float* __restrict__ att_src,
                                                  const float* __restrict__ att_dst,
                                                  __half* __restrict__ h,
                                                  float* __restrict__ a_s,
                                                  float* __restrict__ a_d, int M) {
    __shared__ __align__(16) __half Xs[64 * 128];    // [row][k], XOR-swizzled 16B chunks
    __shared__ __align__(16) __half Ws[128 * 128];   // [perm-slot][k], XOR-swizzled
    const int tid = threadIdx.x;
    const int row0 = blockIdx.x * 64;
    const int by = blockIdx.y;            // 0..1 -> cols by*128..by*128+127
    const int col0 = by * 128;

    for (int t = 0; t < 4; ++t) {
        int c = tid + t * 256;            // 0..1023
        int row = c >> 4, ch = c & 15;
        int r = row0 + row;
        float4 va = make_float4(0.f, 0.f, 0.f, 0.f), vb = va;
        if (r < M) {
            va = *(const float4*)&x[(size_t)r * 128 + ch * 8];
            vb = *(const float4*)&x[(size_t)r * 128 + ch * 8 + 4];
        }
        half8 hv;
        hv[0] = (_Float16)va.x; hv[1] = (_Float16)va.y;
        hv[2] = (_Float16)va.z; hv[3] = (_Float16)va.w;
        hv[4] = (_Float16)vb.x; hv[5] = (_Float16)vb.y;
        hv[6] = (_Float16)vb.z; hv[7] = (_Float16)vb.w;
        *(half8*)((char*)Xs + row * 256 + ((ch * 16) ^ ((row & 7) << 4))) = hv;
    }
    for (int t = 0; t < 8; ++t) {
        int c = tid + t * 256;            // 0..2047
        int n = c >> 4, ch = c & 15;
        int p = ((n & 7) << 4) | (n >> 3);   // permuted LDS slot
        float4 v = *(const float4*)&Wt[(size_t)(col0 + n) * 128 + ch * 8];
        *(float4*)((char*)Ws + p * 256 + ((ch * 16) ^ ((p & 7) << 4))) = v;
    }
    __syncthreads();

    const int w = tid >> 6, lane = tid & 63;
    const int col_l = lane & 15, kgrp = lane >> 4;
    const int arow = w * 16 + col_l;
    const int sw = (col_l & 7) << 4;

    f32x4 acc[8];
#pragma unroll
    for (int nt = 0; nt < 8; ++nt) acc[nt] = (f32x4){0.f, 0.f, 0.f, 0.f};

#pragma unroll
    for (int ks = 0; ks < 4; ++ks) {
        int kchunk = (ks * 4 + kgrp) * 16;
        half8 av = *(const half8*)((const char*)Xs + arow * 256 + (kchunk ^ sw));
#pragma unroll
        for (int nt = 0; nt < 8; ++nt) {
            // slot nt*16+col_l holds logical column col_l*8+nt ((nt*16)&7==0 so swizzle = sw)
            half8 bv = *(const half8*)((const char*)Ws + (nt * 16 + col_l) * 256 + (kchunk ^ sw));
            acc[nt] = __builtin_amdgcn_mfma_f32_16x16x32_f16(av, bv, acc[nt], 0, 0, 0);
        }
    }

    // lane's acc[nt][reg] is C[row=w*16+kgrp*4+reg][col=col_l*8+nt]
    float asv[8], adv[8];
    *(float4*)&asv[0] = *(const float4*)&att_src[col0 + col_l * 8];
    *(float4*)&asv[4] = *(const float4*)&att_src[col0 + col_l * 8 + 4];
    *(float4*)&adv[0] = *(const float4*)&att_dst[col0 + col_l * 8];
    *(float4*)&adv[4] = *(const float4*)&att_dst[col0 + col_l * 8 + 4];

    const int rbase = row0 + w * 16 + kgrp * 4;
#pragma unroll
    for (int reg = 0; reg < 4; ++reg) {
        int gr = rbase + reg;
        if (gr < M) {
            half8 hv;
#pragma unroll
            for (int nt = 0; nt < 8; ++nt) hv[nt] = (_Float16)acc[nt][reg];
            *(half8*)&h[(size_t)gr * 256 + col0 + col_l * 8] = hv;
        }
        float s_ = 0.f, d_ = 0.f;
#pragma unroll
        for (int nt = 0; nt < 8; ++nt) {
            s_ = fmaf(acc[nt][reg], asv[nt], s_);
            d_ = fmaf(acc[nt][reg], adv[nt], d_);
        }
#pragma unroll
        for (int off = 1; off < 16; off <<= 1) {
            s_ += __shfl_xor(s_, off);
            d_ += __shfl_xor(d_, off);
        }
        if (col_l == 0 && gr < M) {
            // by covers 2 heads: head index by*2 + (which 64-col half)... heads are
            // 64-wide; cols col0..col0+127 = heads by*2, by*2+1. s_/d_ summed over
            // all 128 cols would MIX heads — so reduce per 64-col half instead.
            // (handled below; this branch unused)
        }
        // per-head reduction: cols col_l*8.. belong to head (col_l>>3) within this by
        // Redo: split sums into head halves
        float sh0 = 0.f, dh0 = 0.f;
#pragma unroll
        for (int nt = 0; nt < 8; ++nt) { sh0 = s_; dh0 = d_; }
        (void)sh0; (void)dh0;
    }
    // ---- att dots, correct per-head version ----
    // head h_loc = col_l>>3 (0: cols 0..63, 1: cols 64..127 of this by-half)
#pragma unroll
    for (int reg = 0; reg < 4; ++reg) {
        int gr = rbase + reg;
        float s_ = 0.f, d_ = 0.f;
#pragma unroll
        for (int nt = 0; nt < 8; ++nt) {
            s_ = fmaf(acc[nt][reg], asv[nt], s_);
            d_ = fmaf(acc[nt][reg], adv[nt], d_);
        }
        // reduce within 8-lane groups (same head, cols col_l*8 spans 64 cols per 8 lanes)
#pragma unroll
        for (int off = 1; off < 8; off <<= 1) {
            s_ += __shfl_xor(s_, off);
            d_ += __shfl_xor(d_, off);
        }
        if ((col_l & 7) == 0 && gr < M) {
            int head = by * 2 + (col_l >> 3);
            a_s[(size_t)gr * 4 + head] = s_;
            a_d[(size_t)gr * 4 + head] = d_;
        }
    }
}

// ---------------- agg layer 1 (fused softmax): wave-per-node ----------------

__global__ __launch_bounds__(256) void k_agg1(const __half* __restrict__ h1,
                                              const int* __restrict__ row_ptr,
                                              const int* __restrict__ esrc,
                                              const float* __restrict__ asrc,
                                              const float* __restrict__ adst,
                                              const float* __restrict__ b1,
                                              __half* __restrict__ y1, int N) {
    __shared__ int ss[4][64];
    __shared__ float sa[4][64 * 4];
    int tid = threadIdx.x;
    int wv = tid >> 6, lane = tid & 63;
    int n = blockIdx.x * 4 + wv;
    if (n >= N) return;
    int head = lane >> 4;
    int e0 = row_ptr[n], e1 = row_ptr[n + 1];
    int deg = e1 - e0;
    const float4 ad = *(const float4*)&adst[(size_t)n * 4];
    float4 acc = make_float4(0.f, 0.f, 0.f, 0.f);
    float4 asum = make_float4(0.f, 0.f, 0.f, 0.f);

    if (deg <= 64) {
        float4 l = make_float4(-3e38f, -3e38f, -3e38f, -3e38f);
        if (lane < deg) {
            int s = esrc[e0 + lane];
            ss[wv][lane] = s;
            float4 as = *(const float4*)&asrc[(size_t)s * 4];
            l.x = lrelu(as.x + ad.x); l.y = lrelu(as.y + ad.y);
            l.z = lrelu(as.z + ad.z); l.w = lrelu(as.w + ad.w);
        }
        float4 m = l;
#pragma unroll
        for (int off = 1; off < 64; off <<= 1) {
            m.x = fmaxf(m.x, __shfl_xor(m.x, off));
            m.y = fmaxf(m.y, __shfl_xor(m.y, off));
            m.z = fmaxf(m.z, __shfl_xor(m.z, off));
            m.w = fmaxf(m.w, __shfl_xor(m.w, off));
        }
        float4 a = make_float4(0.f, 0.f, 0.f, 0.f);
        if (lane < deg) {
            a.x = __expf(l.x - m.x); a.y = __expf(l.y - m.y);
            a.z = __expf(l.z - m.z); a.w = __expf(l.w - m.w);
            *(float4*)&sa[wv][lane * 4] = a;
        }
        asum = a;
        int i = 0;
        for (; i + 3 < deg; i += 4) {
            int s0 = ss[wv][i], s1 = ss[wv][i + 1], s2 = ss[wv][i + 2], s3 = ss[wv][i + 3];
            float a0 = sa[wv][i * 4 + head],       a1 = sa[wv][(i + 1) * 4 + head];
            float a2 = sa[wv][(i + 2) * 4 + head], a3 = sa[wv][(i + 3) * 4 + head];
            float2 r0 = *(const float2*)&h1[(size_t)s0 * 256 + lane * 4];
            float2 r1 = *(const float2*)&h1[(size_t)s1 * 256 + lane * 4];
            float2 r2 = *(const float2*)&h1[(size_t)s2 * 256 + lane * 4];
            float2 r3 = *(const float2*)&h1[(size_t)s3 * 256 + lane * 4];
            fma4(a0, h4_to_f4(r0), acc);
            fma4(a1, h4_to_f4(r1), acc);
            fma4(a2, h4_to_f4(r2), acc);
            fma4(a3, h4_to_f4(r3), acc);
        }
        for (; i < deg; ++i) {
            int s0 = ss[wv][i];
            float a0 = sa[wv][i * 4 + head];
            float2 r0 = *(const float2*)&h1[(size_t)s0 * 256 + lane * 4];
            fma4(a0, h4_to_f4(r0), acc);
        }
    } else {
        float4 m = make_float4(-3e38f, -3e38f, -3e38f, -3e38f);
        for (int p0 = e0; p0 < e1; p0 += 64) {
            int e = p0 + lane;
            if (e < e1) {
                int s = esrc[e];
                float4 as = *(const float4*)&asrc[(size_t)s * 4];
                m.x = fmaxf(m.x, lrelu(as.x + ad.x));
                m.y = fmaxf(m.y, lrelu(as.y + ad.y));
                m.z = fmaxf(m.z, lrelu(as.z + ad.z));
                m.w = fmaxf(m.w, lrelu(as.w + ad.w));
            }
        }
#pragma unroll
        for (int off = 1; off < 64; off <<= 1) {
            m.x = fmaxf(m.x, __shfl_xor(m.x, off));
            m.y = fmaxf(m.y, __shfl_xor(m.y, off));
            m.z = fmaxf(m.z, __shfl_xor(m.z, off));
            m.w = fmaxf(m.w, __shfl_xor(m.w, off));
        }
        for (int p0 = e0; p0 < e1; p0 += 64) {
            int cnt = min(64, e1 - p0);
            if (lane < cnt) {
                int s = esrc[p0 + lane];
                ss[wv][lane] = s;
                float4 as = *(const float4*)&asrc[(size_t)s * 4];
                float4 a;
                a.x = __expf(lrelu(as.x + ad.x) - m.x);
                a.y = __expf(lrelu(as.y + ad.y) - m.y);
                a.z = __expf(lrelu(as.z + ad.z) - m.z);
                a.w = __expf(lrelu(as.w + ad.w) - m.w);
                *(float4*)&sa[wv][lane * 4] = a;
                asum.x += a.x; asum.y += a.y; asum.z += a.z; asum.w += a.w;
            }
            int i = 0;
            for (; i + 3 < cnt; i += 4) {
                int s0 = ss[wv][i], s1 = ss[wv][i + 1], s2 = ss[wv][i + 2], s3 = ss[wv][i + 3];
                float a0 = sa[wv][i * 4 + head],       a1 = sa[wv][(i + 1) * 4 + head];
                float a2 = sa[wv][(i + 2) * 4 + head], a3 = sa[wv][(i + 3) * 4 + head];
                float2 r0 = *(const float2*)&h1[(size_t)s0 * 256 + lane * 4];
                float2 r1 = *(const float2*)&h1[(size_t)s1 * 256 + lane * 4];
                float2 r2 = *(const float2*)&h1[(size_t)s2 * 256 + lane * 4];
                float2 r3 = *(const float2*)&h1[(size_t)s3 * 256 + lane * 4];
                fma4(a0, h4_to_f4(r0), acc);
                fma4(a1, h4_to_f4(r1), acc);
                fma4(a2, h4_to_f4(r2), acc);
                fma4(a3, h4_to_f4(r3), acc);
            }
            for (; i < cnt; ++i) {
                int s0 = ss[wv][i];
                float a0 = sa[wv][i * 4 + head];
                float2 r0 = *(const float2*)&h1[(size_t)s0 * 256 + lane * 4];
                fma4(a0, h4_to_f4(r0), acc);
            }
        }
    }

#pragma unroll
    for (int off = 1; off < 64; off <<= 1) {
        asum.x += __shfl_xor(asum.x, off);
        asum.y += __shfl_xor(asum.y, off);
        asum.z += __shfl_xor(asum.z, off);
        asum.w += __shfl_xor(asum.w, off);
    }
    float ssum = (head == 0) ? asum.x : (head == 1) ? asum.y : (head == 2) ? asum.z : asum.w;
    float inv = 1.f / (ssum + 1e-16f);
    float4 bb = *(const float4*)&b1[lane * 4];
    float4 v;
    v.x = acc.x * inv + bb.x; v.y = acc.y * inv + bb.y;
    v.z = acc.z * inv + bb.z; v.w = acc.w * inv + bb.w;
    v.x = (v.x > 0.f) ? v.x : (__expf(v.x) - 1.f);
    v.y = (v.y > 0.f) ? v.y : (__expf(v.y) - 1.f);
    v.z = (v.z > 0.f) ? v.z : (__expf(v.z) - 1.f);
    v.w = (v.w > 0.f) ? v.w : (__expf(v.w) - 1.f);
    __half2 h01 = __floats2half2_rn(v.x, v.y);
    __half2 h23 = __floats2half2_rn(v.z, v.w);
    float2 st;
    *(__half2*)&st.x = h01;
    *(__half2*)&st.y = h23;
    *(float2*)&y1[(size_t)n * 256 + lane * 4] = st;
}

// ---------------- GEMM2 (MFMA fp16): h2 = y1 @ W2, fused att dots ----------------

__global__ __launch_bounds__(256, 3) void k_gemm2(const __half* __restrict__ y1,
                                                  const __half* __restrict__ W2t,
                                                  const float* __restrict__ att_src,
                                                  const float* __restrict__ att_dst,
                                                  __half* __restrict__ h2,
                                                  float* __restrict__ a_s,
                                                  float* __restrict__ a_d, int M) {
    __shared__ __align__(16) __half Ys[64 * 256];    // 32KB, swizzled
    __shared__ __align__(16) __half Ws[32 * 256];    // 16KB, swizzled, permuted slots
    const int tid = threadIdx.x;
    const int row0 = blockIdx.x * 64;

    for (int t = 0; t < 8; ++t) {
        int c = tid + t * 256;            // 0..2047
        int row = c >> 5, ch = c & 31;
        int r = row0 + row;
        float4 v = make_float4(0.f, 0.f, 0.f, 0.f);
        if (r < M) v = *(const float4*)&y1[(size_t)r * 256 + ch * 8];
        *(float4*)((char*)Ys + row * 512 + ((ch * 16) ^ ((row & 7) << 4))) = v;
    }
    for (int t = 0; t < 4; ++t) {
        int c = tid + t * 256;            // 0..1023
        int n = c >> 5, ch = c & 31;
        int p = ((n & 1) << 4) | (n >> 1);     // permuted slot: lane col_l holds cols col_l*2+nt
        float4 v = *(const float4*)&W2t[(size_t)n * 256 + ch * 8];
        *(float4*)((char*)Ws + p * 512 + ((ch * 16) ^ ((p & 7) << 4))) = v;
    }
    __syncthreads();

    const int w = tid >> 6, lane = tid & 63;
    const int col_l = lane & 15, kgrp = lane >> 4;
    const int arow = w * 16 + col_l;
    const int sw = (col_l & 7) << 4;

    f32x4 acc[2];
    acc[0] = (f32x4){0.f, 0.f, 0.f, 0.f};
    acc[1] = (f32x4){0.f, 0.f, 0.f, 0.f};

#pragma unroll
    for (int ks = 0; ks < 8; ++ks) {
        int kchunk = (ks * 4 + kgrp) * 16;
        half8 av = *(const half8*)((const char*)Ys + arow * 512 + (kchunk ^ sw));
#pragma unroll
        for (int nt = 0; nt < 2; ++nt) {
            half8 bv = *(const half8*)((const char*)Ws + (nt * 16 + col_l) * 512 + (kchunk ^ sw));
            acc[nt] = __builtin_amdgcn_mfma_f32_16x16x32_f16(av, bv, acc[nt], 0, 0, 0);
        }
    }

    // lane's acc[nt][reg] = C[row][col = col_l*2 + nt]
    float asv[2], adv[2];
    asv[0] = att_src[col_l * 2]; asv[1] = att_src[col_l * 2 + 1];
    adv[0] = att_dst[col_l * 2]; adv[1] = att_dst[col_l * 2 + 1];
    const int rbase = row0 + w * 16 + kgrp * 4;
#pragma unroll
    for (int reg = 0; reg < 4; ++reg) {
        int gr = rbase + reg;
        if (gr < M) {
            __half2 hv = __floats2half2_rn(acc[0][reg], acc[1][reg]);
            *(__half2*)&h2[(size_t)gr * 32 + col_l * 2] = hv;
        }
        float s_ = fmaf(acc[0][reg], asv[0], acc[1][reg] * asv[1]);
        float d_ = fmaf(acc[0][reg], adv[0], acc[1][reg] * adv[1]);
#pragma unroll
        for (int off = 1; off < 16; off <<= 1) {
            s_ += __shfl_xor(s_, off);
            d_ += __shfl_xor(d_, off);
        }
        if (col_l == 0 && gr < M) { a_s[gr] = s_; a_d[gr] = d_; }
    }
}

// ---------------- agg layer 2 (fused softmax): wave-per-node ----------------

__global__ __launch_bounds__(256) void k_agg2(const __half* __restrict__ h2,
                                              const int* __restrict__ row_ptr,
                                              const int* __restrict__ esrc,
                                              const float* __restrict__ asrc,
                                              const float* __restrict__ adst,
                                              const float* __restrict__ b2,
                                              float* __restrict__ out, int N) {
    __shared__ int ss[4][64];
    __shared__ float sa[4][64];
    int tid = threadIdx.x;
    int wv = tid >> 6, lane = tid & 63;
    int n = blockIdx.x * 4 + wv;
    if (n >= N) return;
    int grp = lane >> 4, cl = lane & 15;
    int e0 = row_ptr[n], e1 = row_ptr[n + 1];
    int deg = e1 - e0;
    float ad = adst[n];
    float2 acc = make_float2(0.f, 0.f);
    float asum = 0.f;

    auto gather = [&](int cnt) {
        int i = 0;
        for (; i + 7 < cnt; i += 8) {
            int ea = i + grp, eb = i + 4 + grp;
            int s0 = ss[wv][ea], s1 = ss[wv][eb];
            float a0 = sa[wv][ea], a1 = sa[wv][eb];
            __half2 v0 = *(const __half2*)&h2[(size_t)s0 * 32 + cl * 2];
            __half2 v1 = *(const __half2*)&h2[(size_t)s1 * 32 + cl * 2];
            float2 f0 = __half22float2(v0), f1 = __half22float2(v1);
            acc.x = fmaf(a0, f0.x, acc.x); acc.y = fmaf(a0, f0.y, acc.y);
            acc.x = fmaf(a1, f1.x, acc.x); acc.y = fmaf(a1, f1.y, acc.y);
        }
        for (; i < cnt; i += 4) {
            int e = i + grp;
            if (e < cnt) {
                int s0 = ss[wv][e];
                float a0 = sa[wv][e];
                __half2 v0 = *(const __half2*)&h2[(size_t)s0 * 32 + cl * 2];
                float2 f0 = __half22float2(v0);
                acc.x = fmaf(a0, f0.x, acc.x); acc.y = fmaf(a0, f0.y, acc.y);
            }
        }
    };

    if (deg <= 64) {
        float l = -3e38f;
        if (lane < deg) {
            int s = esrc[e0 + lane];
            ss[wv][lane] = s;
            l = lrelu(asrc[s] + ad);
        }
        float m = l;
#pragma unroll
        for (int off = 1; off < 64; off <<= 1) m = fmaxf(m, __shfl_xor(m, off));
        float a = 0.f;
        if (lane < deg) {
            a = __expf(l - m);
            sa[wv][lane] = a;
        }
        asum = a;
        gather(deg);
    } else {
        float m = -3e38f;
        for (int p0 = e0; p0 < e1; p0 += 64) {
            int e = p0 + lane;
            if (e < e1) m = fmaxf(m, lrelu(asrc[esrc[e]] + ad));
        }
#pragma unroll
        for (int off = 1; off < 64; off <<= 1) m = fmaxf(m, __shfl_xor(m, off));
        for (int p0 = e0; p0 < e1; p0 += 64) {
            int cnt = min(64, e1 - p0);
            if (lane < cnt) {
                int s = esrc[p0 + lane];
                ss[wv][lane] = s;
                float a = __expf(lrelu(asrc[s] + ad) - m);
                sa[wv][lane] = a;
                asum += a;
            }
            gather(cnt);
        }
    }

    acc.x += __shfl_xor(acc.x, 16); acc.y += __shfl_xor(acc.y, 16);
    acc.x += __shfl_xor(acc.x, 32); acc.y += __shfl_xor(acc.y, 32);
#pragma unroll
    for (int off = 1; off < 64; off <<= 1) asum += __shfl_xor(asum, off);
    if (grp == 0) {
        float inv = 1.f / (asum + 1e-16f);
        float2 o;
        o.x = acc.x * inv + b2[cl * 2];
        o.y = acc.y * inv + b2[cl * 2 + 1];
        *(float2*)&out[(size_t)n * 32 + cl * 2] = o;
    }
}

// ---------------- launcher ----------------

extern "C" void kernel_launch(void* const* d_in, const int* in_sizes, int n_in,
                              void* d_out, int out_size, void* d_ws, size_t ws_size,
                              hipStream_t stream) {
    const float* x   = (const float*)d_in[0];
    const int*   ei  = (const int*)d_in[1];
    const float* W1  = (const float*)d_in[2];
    const float* as1 = (const float*)d_in[3];
    const float* ad1 = (const float*)d_in[4];
    const float* b1  = (const float*)d_in[5];
    const float* W2  = (const float*)d_in[6];
    const float* as2 = (const float*)d_in[7];
    const float* ad2 = (const float*)d_in[8];
    const float* b2  = (const float*)d_in[9];
    float* out = (float*)d_out;

    const int N = in_sizes[0] / 128;   // 50000
    const int E = in_sizes[1] / 2;     // 800000
    const int* src = ei;
    const int* dstp = ei + E;
    const int nb = (N + 1023) / 1024;

    char* ws = (char*)d_ws;
    size_t off = 0;
    auto alloc = [&](size_t nbytes) {
        void* p = ws + off;
        off += (nbytes + 255) & ~(size_t)255;
        return p;
    };
    int* counts    = (int*)alloc((size_t)N * 4);
    int* row_ptr   = (int*)alloc((size_t)(N + 1) * 4);
    int* row_fill  = (int*)alloc((size_t)N * 4);
    int* esrc      = (int*)alloc((size_t)E * 4);
    __half* h1     = (__half*)alloc((size_t)N * 256 * 2);
    __half* y1     = (__half*)alloc((size_t)N * 256 * 2);
    __half* h2     = (__half*)alloc((size_t)N * 32 * 2);
    float* a_s1    = (float*)alloc((size_t)N * 4 * 4);
    float* a_d1    = (float*)alloc((size_t)N * 4 * 4);
    float* a_s2    = (float*)alloc((size_t)N * 4);
    float* a_d2    = (float*)alloc((size_t)N * 4);
    int* bsum      = (int*)alloc((size_t)nb * 4);
    int* boff      = (int*)alloc((size_t)nb * 4);
    __half* Wt     = (__half*)alloc((size_t)256 * 128 * 2);
    __half* W2t    = (__half*)alloc((size_t)32 * 256 * 2);

    hipMemsetAsync(counts, 0, (size_t)N * 4, stream);
    k_hist<<<(E + 255) / 256, 256, 0, stream>>>(dstp, counts, E);
    k_scan1<<<nb, 256, 0, stream>>>(counts, bsum, N);
    k_scan2<<<1, 64, 0, stream>>>(bsum, boff, &row_ptr[N], nb);
    k_scan3<<<nb, 256, 0, stream>>>(counts, boff, row_ptr, row_fill, N);
    k_scatter<<<(E + 255) / 256, 256, 0, stream>>>(src, dstp, row_fill, esrc, E);

    k_wt<<<288, 256, 0, stream>>>(W1, W2, Wt, W2t);

    k_gemm1<<<dim3((N + 63) / 64, 2), 256, 0, stream>>>(x, Wt, as1, ad1, h1, a_s1, a_d1, N);
    k_agg1<<<(N + 3) / 4, 256, 0, stream>>>(h1, row_ptr, esrc, a_s1, a_d1, b1, y1, N);

    k_gemm2<<<(N + 63) / 64, 256, 0, stream>>>(y1, W2t, as2, ad2, h2, a_s2, a_d2, N);
    k_agg2<<<(N + 3) / 4, 256, 0, stream>>>(h2, row_ptr, esrc, a_s2, a_d2, b2, out, N);
}

// Round 11
// 216.131 us; speedup vs baseline: 2.6174x; 1.0040x over previous
//
#include <hip/hip_runtime.h>
#include <hip/hip_bf16.h>
#include <hip/hip_fp16.h>

#define NEG_SLOPE 0.2f

typedef _Float16 half8 __attribute__((ext_vector_type(8)));
typedef float f32x4 __attribute__((ext_vector_type(4)));

__device__ __forceinline__ float lrelu(float x) { return x >= 0.f ? x : NEG_SLOPE * x; }

__device__ __forceinline__ float4 h4_to_f4(float2 r) {
    __half2 a = *(__half2*)&r.x;
    __half2 b = *(__half2*)&r.y;
    float2 fa = __half22float2(a), fb = __half22float2(b);
    return make_float4(fa.x, fa.y, fb.x, fb.y);
}

__device__ __forceinline__ void fma4(float a, float4 v, float4& acc) {
    acc.x = fmaf(a, v.x, acc.x); acc.y = fmaf(a, v.y, acc.y);
    acc.z = fmaf(a, v.z, acc.z); acc.w = fmaf(a, v.w, acc.w);
}

// ---------------- CSR construction ----------------

__global__ void k_hist(const int* __restrict__ dst, int* __restrict__ counts, int E) {
    int e = blockIdx.x * 256 + threadIdx.x;
    if (e < E) atomicAdd(&counts[dst[e]], 1);
}

__global__ __launch_bounds__(256) void k_scan1(const int* __restrict__ counts,
                                               int* __restrict__ bsum, int N) {
    __shared__ int wsum[4];
    int b = blockIdx.x, t = threadIdx.x;
    int i0 = b * 1024 + t * 4;
    int s = 0;
    if (i0 < N) { int4 v = *(const int4*)&counts[i0]; s = v.x + v.y + v.z + v.w; }
#pragma unroll
    for (int off = 32; off; off >>= 1) s += __shfl_down(s, off);
    if ((t & 63) == 0) wsum[t >> 6] = s;
    __syncthreads();
    if (t == 0) bsum[b] = wsum[0] + wsum[1] + wsum[2] + wsum[3];
}

__global__ void k_scan2(const int* __restrict__ bsum, int* __restrict__ boff,
                        int* __restrict__ row_ptrN, int nb) {
    int t = threadIdx.x;  // 64 threads, nb <= 64
    int v = (t < nb) ? bsum[t] : 0;
    int incl = v;
#pragma unroll
    for (int off = 1; off < 64; off <<= 1) {
        int u = __shfl_up(incl, off);
        if (t >= off) incl += u;
    }
    if (t < nb) boff[t] = incl - v;
    if (t == nb - 1) *row_ptrN = incl;
}

__global__ __launch_bounds__(256) void k_scan3(const int* __restrict__ counts,
                                               const int* __restrict__ boff,
                                               int* __restrict__ row_ptr,
                                               int* __restrict__ row_fill, int N) {
    __shared__ int lds[256];
    int b = blockIdx.x, t = threadIdx.x;
    int i0 = b * 1024 + t * 4;
    int4 v = make_int4(0, 0, 0, 0);
    if (i0 < N) v = *(const int4*)&counts[i0];
    int tot = v.x + v.y + v.z + v.w;
    lds[t] = tot;
    __syncthreads();
    for (int off = 1; off < 256; off <<= 1) {
        int u = (t >= off) ? lds[t - off] : 0;
        __syncthreads();
        lds[t] += u;
        __syncthreads();
    }
    int excl = lds[t] - tot;
    int run = boff[b] + excl;
    if (i0 < N) {
        row_ptr[i0] = run;     row_fill[i0] = run;     run += v.x;
        row_ptr[i0 + 1] = run; row_fill[i0 + 1] = run; run += v.y;
        row_ptr[i0 + 2] = run; row_fill[i0 + 2] = run; run += v.z;
        row_ptr[i0 + 3] = run; row_fill[i0 + 3] = run;
    }
}

__global__ void k_scatter(const int* __restrict__ src, const int* __restrict__ dst,
                          int* __restrict__ row_fill, int* __restrict__ esrc, int E) {
    int e = blockIdx.x * 256 + threadIdx.x;
    if (e < E) {
        int p = atomicAdd(&row_fill[dst[e]], 1);
        esrc[p] = src[e];
    }
}

// ---------------- weight transposes to fp16 (merged) ----------------

__global__ __launch_bounds__(256) void k_wt(const float* __restrict__ W1,
                                            const float* __restrict__ W2,
                                            __half* __restrict__ W1t,
                                            __half* __restrict__ W2t) {
    int b = blockIdx.x, k = threadIdx.x;
    if (b < 256) {
        if (k < 128) W1t[b * 128 + k] = __float2half(W1[(size_t)k * 256 + b]);
    } else {
        int n = b - 256;   // 0..31
        W2t[n * 256 + k] = __float2half(W2[(size_t)k * 32 + n]);
    }
}

// ---------------- GEMM1 (MFMA fp16): h1 = x @ W1, fused att dots ----------------
// 128x128 tile per block (2x arithmetic intensity per LDS stage vs 64x128).
// Wave w owns rows w*32..w*32+31 (2 m-tiles). Column permutation keeps each
// lane's 8 n-tile outputs contiguous -> 16B coalesced stores.

__global__ __launch_bounds__(256, 2) void k_gemm1(const float* __restrict__ x,
                                                  const __half* __restrict__ Wt,
                                                  const float* __restrict__ att_src,
                                                  const float* __restrict__ att_dst,
                                                  __half* __restrict__ h,
                                                  float* __restrict__ a_s,
                                                  float* __restrict__ a_d, int M) {
    __shared__ __align__(16) __half Xs[128 * 128];   // [row][k], XOR-swizzled 16B chunks
    __shared__ __align__(16) __half Ws[128 * 128];   // [perm-slot][k], XOR-swizzled
    const int tid = threadIdx.x;
    const int row0 = blockIdx.x * 128;
    const int by = blockIdx.y;            // 0..1 -> cols by*128..by*128+127
    const int col0 = by * 128;

    // stage X: 128 rows x 16 chunks (16B = 8 fp16), fp32->fp16
    for (int t = 0; t < 8; ++t) {
        int c = tid + t * 256;            // 0..2047
        int row = c >> 4, ch = c & 15;
        int r = row0 + row;
        float4 va = make_float4(0.f, 0.f, 0.f, 0.f), vb = va;
        if (r < M) {
            va = *(const float4*)&x[(size_t)r * 128 + ch * 8];
            vb = *(const float4*)&x[(size_t)r * 128 + ch * 8 + 4];
        }
        half8 hv;
        hv[0] = (_Float16)va.x; hv[1] = (_Float16)va.y;
        hv[2] = (_Float16)va.z; hv[3] = (_Float16)va.w;
        hv[4] = (_Float16)vb.x; hv[5] = (_Float16)vb.y;
        hv[6] = (_Float16)vb.z; hv[7] = (_Float16)vb.w;
        *(half8*)((char*)Xs + row * 256 + ((ch * 16) ^ ((row & 7) << 4))) = hv;
    }
    // stage Wt cols col0..col0+127, permuted slots
    for (int t = 0; t < 8; ++t) {
        int c = tid + t * 256;            // 0..2047
        int n = c >> 4, ch = c & 15;
        int p = ((n & 7) << 4) | (n >> 3);   // permuted LDS slot
        float4 v = *(const float4*)&Wt[(size_t)(col0 + n) * 128 + ch * 8];
        *(float4*)((char*)Ws + p * 256 + ((ch * 16) ^ ((p & 7) << 4))) = v;
    }
    __syncthreads();

    const int w = tid >> 6, lane = tid & 63;
    const int col_l = lane & 15, kgrp = lane >> 4;
    const int sw = (col_l & 7) << 4;
    const int arow0 = w * 32 + col_l;          // m-tile 0
    const int arow1 = arow0 + 16;              // m-tile 1 (same swizzle: (16+c)&7 == c&7)

    f32x4 acc[2][8];
#pragma unroll
    for (int mt = 0; mt < 2; ++mt)
#pragma unroll
        for (int nt = 0; nt < 8; ++nt) acc[mt][nt] = (f32x4){0.f, 0.f, 0.f, 0.f};

#pragma unroll
    for (int ks = 0; ks < 4; ++ks) {
        int kchunk = (ks * 4 + kgrp) * 16;
        half8 av0 = *(const half8*)((const char*)Xs + arow0 * 256 + (kchunk ^ sw));
        half8 av1 = *(const half8*)((const char*)Xs + arow1 * 256 + (kchunk ^ sw));
#pragma unroll
        for (int nt = 0; nt < 8; ++nt) {
            half8 bv = *(const half8*)((const char*)Ws + (nt * 16 + col_l) * 256 + (kchunk ^ sw));
            acc[0][nt] = __builtin_amdgcn_mfma_f32_16x16x32_f16(av0, bv, acc[0][nt], 0, 0, 0);
            acc[1][nt] = __builtin_amdgcn_mfma_f32_16x16x32_f16(av1, bv, acc[1][nt], 0, 0, 0);
        }
    }

    // lane's acc[mt][nt][reg] = C[row0 + w*32 + mt*16 + kgrp*4 + reg][col0 + col_l*8 + nt]
    float asv[8], adv[8];
    *(float4*)&asv[0] = *(const float4*)&att_src[col0 + col_l * 8];
    *(float4*)&asv[4] = *(const float4*)&att_src[col0 + col_l * 8 + 4];
    *(float4*)&adv[0] = *(const float4*)&att_dst[col0 + col_l * 8];
    *(float4*)&adv[4] = *(const float4*)&att_dst[col0 + col_l * 8 + 4];

#pragma unroll
    for (int mt = 0; mt < 2; ++mt) {
        const int rbase = row0 + w * 32 + mt * 16 + kgrp * 4;
#pragma unroll
        for (int reg = 0; reg < 4; ++reg) {
            int gr = rbase + reg;
            if (gr < M) {
                half8 hv;
#pragma unroll
                for (int nt = 0; nt < 8; ++nt) hv[nt] = (_Float16)acc[mt][nt][reg];
                *(half8*)&h[(size_t)gr * 256 + col0 + col_l * 8] = hv;
            }
            float s_ = 0.f, d_ = 0.f;
#pragma unroll
            for (int nt = 0; nt < 8; ++nt) {
                s_ = fmaf(acc[mt][nt][reg], asv[nt], s_);
                d_ = fmaf(acc[mt][nt][reg], adv[nt], d_);
            }
            // reduce within 8-lane group (one head = cols h*64..h*64+63 = 8 lanes x 8 cols)
#pragma unroll
            for (int off = 1; off < 8; off <<= 1) {
                s_ += __shfl_xor(s_, off);
                d_ += __shfl_xor(d_, off);
            }
            if ((col_l & 7) == 0 && gr < M) {
                int head = by * 2 + (col_l >> 3);
                a_s[(size_t)gr * 4 + head] = s_;
                a_d[(size_t)gr * 4 + head] = d_;
            }
        }
    }
}

// ---------------- agg layer 1 (fused softmax): wave-per-node ----------------

__global__ __launch_bounds__(256) void k_agg1(const __half* __restrict__ h1,
                                              const int* __restrict__ row_ptr,
                                              const int* __restrict__ esrc,
                                              const float* __restrict__ asrc,
                                              const float* __restrict__ adst,
                                              const float* __restrict__ b1,
                                              __half* __restrict__ y1, int N) {
    __shared__ int ss[4][64];
    __shared__ float sa[4][64 * 4];
    int tid = threadIdx.x;
    int wv = tid >> 6, lane = tid & 63;
    int n = blockIdx.x * 4 + wv;
    if (n >= N) return;
    int head = lane >> 4;
    int e0 = row_ptr[n], e1 = row_ptr[n + 1];
    int deg = e1 - e0;
    const float4 ad = *(const float4*)&adst[(size_t)n * 4];
    float4 acc = make_float4(0.f, 0.f, 0.f, 0.f);
    float4 asum = make_float4(0.f, 0.f, 0.f, 0.f);

    if (deg <= 64) {
        float4 l = make_float4(-3e38f, -3e38f, -3e38f, -3e38f);
        if (lane < deg) {
            int s = esrc[e0 + lane];
            ss[wv][lane] = s;
            float4 as = *(const float4*)&asrc[(size_t)s * 4];
            l.x = lrelu(as.x + ad.x); l.y = lrelu(as.y + ad.y);
            l.z = lrelu(as.z + ad.z); l.w = lrelu(as.w + ad.w);
        }
        float4 m = l;
#pragma unroll
        for (int off = 1; off < 64; off <<= 1) {
            m.x = fmaxf(m.x, __shfl_xor(m.x, off));
            m.y = fmaxf(m.y, __shfl_xor(m.y, off));
            m.z = fmaxf(m.z, __shfl_xor(m.z, off));
            m.w = fmaxf(m.w, __shfl_xor(m.w, off));
        }
        float4 a = make_float4(0.f, 0.f, 0.f, 0.f);
        if (lane < deg) {
            a.x = __expf(l.x - m.x); a.y = __expf(l.y - m.y);
            a.z = __expf(l.z - m.z); a.w = __expf(l.w - m.w);
            *(float4*)&sa[wv][lane * 4] = a;
        }
        asum = a;
        int i = 0;
        for (; i + 3 < deg; i += 4) {
            int s0 = ss[wv][i], s1 = ss[wv][i + 1], s2 = ss[wv][i + 2], s3 = ss[wv][i + 3];
            float a0 = sa[wv][i * 4 + head],       a1 = sa[wv][(i + 1) * 4 + head];
            float a2 = sa[wv][(i + 2) * 4 + head], a3 = sa[wv][(i + 3) * 4 + head];
            float2 r0 = *(const float2*)&h1[(size_t)s0 * 256 + lane * 4];
            float2 r1 = *(const float2*)&h1[(size_t)s1 * 256 + lane * 4];
            float2 r2 = *(const float2*)&h1[(size_t)s2 * 256 + lane * 4];
            float2 r3 = *(const float2*)&h1[(size_t)s3 * 256 + lane * 4];
            fma4(a0, h4_to_f4(r0), acc);
            fma4(a1, h4_to_f4(r1), acc);
            fma4(a2, h4_to_f4(r2), acc);
            fma4(a3, h4_to_f4(r3), acc);
        }
        for (; i < deg; ++i) {
            int s0 = ss[wv][i];
            float a0 = sa[wv][i * 4 + head];
            float2 r0 = *(const float2*)&h1[(size_t)s0 * 256 + lane * 4];
            fma4(a0, h4_to_f4(r0), acc);
        }
    } else {
        float4 m = make_float4(-3e38f, -3e38f, -3e38f, -3e38f);
        for (int p0 = e0; p0 < e1; p0 += 64) {
            int e = p0 + lane;
            if (e < e1) {
                int s = esrc[e];
                float4 as = *(const float4*)&asrc[(size_t)s * 4];
                m.x = fmaxf(m.x, lrelu(as.x + ad.x));
                m.y = fmaxf(m.y, lrelu(as.y + ad.y));
                m.z = fmaxf(m.z, lrelu(as.z + ad.z));
                m.w = fmaxf(m.w, lrelu(as.w + ad.w));
            }
        }
#pragma unroll
        for (int off = 1; off < 64; off <<= 1) {
            m.x = fmaxf(m.x, __shfl_xor(m.x, off));
            m.y = fmaxf(m.y, __shfl_xor(m.y, off));
            m.z = fmaxf(m.z, __shfl_xor(m.z, off));
            m.w = fmaxf(m.w, __shfl_xor(m.w, off));
        }
        for (int p0 = e0; p0 < e1; p0 += 64) {
            int cnt = min(64, e1 - p0);
            if (lane < cnt) {
                int s = esrc[p0 + lane];
                ss[wv][lane] = s;
                float4 as = *(const float4*)&asrc[(size_t)s * 4];
                float4 a;
                a.x = __expf(lrelu(as.x + ad.x) - m.x);
                a.y = __expf(lrelu(as.y + ad.y) - m.y);
                a.z = __expf(lrelu(as.z + ad.z) - m.z);
                a.w = __expf(lrelu(as.w + ad.w) - m.w);
                *(float4*)&sa[wv][lane * 4] = a;
                asum.x += a.x; asum.y += a.y; asum.z += a.z; asum.w += a.w;
            }
            int i = 0;
            for (; i + 3 < cnt; i += 4) {
                int s0 = ss[wv][i], s1 = ss[wv][i + 1], s2 = ss[wv][i + 2], s3 = ss[wv][i + 3];
                float a0 = sa[wv][i * 4 + head],       a1 = sa[wv][(i + 1) * 4 + head];
                float a2 = sa[wv][(i + 2) * 4 + head], a3 = sa[wv][(i + 3) * 4 + head];
                float2 r0 = *(const float2*)&h1[(size_t)s0 * 256 + lane * 4];
                float2 r1 = *(const float2*)&h1[(size_t)s1 * 256 + lane * 4];
                float2 r2 = *(const float2*)&h1[(size_t)s2 * 256 + lane * 4];
                float2 r3 = *(const float2*)&h1[(size_t)s3 * 256 + lane * 4];
                fma4(a0, h4_to_f4(r0), acc);
                fma4(a1, h4_to_f4(r1), acc);
                fma4(a2, h4_to_f4(r2), acc);
                fma4(a3, h4_to_f4(r3), acc);
            }
            for (; i < cnt; ++i) {
                int s0 = ss[wv][i];
                float a0 = sa[wv][i * 4 + head];
                float2 r0 = *(const float2*)&h1[(size_t)s0 * 256 + lane * 4];
                fma4(a0, h4_to_f4(r0), acc);
            }
        }
    }

#pragma unroll
    for (int off = 1; off < 64; off <<= 1) {
        asum.x += __shfl_xor(asum.x, off);
        asum.y += __shfl_xor(asum.y, off);
        asum.z += __shfl_xor(asum.z, off);
        asum.w += __shfl_xor(asum.w, off);
    }
    float ssum = (head == 0) ? asum.x : (head == 1) ? asum.y : (head == 2) ? asum.z : asum.w;
    float inv = 1.f / (ssum + 1e-16f);
    float4 bb = *(const float4*)&b1[lane * 4];
    float4 v;
    v.x = acc.x * inv + bb.x; v.y = acc.y * inv + bb.y;
    v.z = acc.z * inv + bb.z; v.w = acc.w * inv + bb.w;
    v.x = (v.x > 0.f) ? v.x : (__expf(v.x) - 1.f);
    v.y = (v.y > 0.f) ? v.y : (__expf(v.y) - 1.f);
    v.z = (v.z > 0.f) ? v.z : (__expf(v.z) - 1.f);
    v.w = (v.w > 0.f) ? v.w : (__expf(v.w) - 1.f);
    __half2 h01 = __floats2half2_rn(v.x, v.y);
    __half2 h23 = __floats2half2_rn(v.z, v.w);
    float2 st;
    *(__half2*)&st.x = h01;
    *(__half2*)&st.y = h23;
    *(float2*)&y1[(size_t)n * 256 + lane * 4] = st;
}

// ---------------- GEMM2 (MFMA fp16): h2 = y1 @ W2, fused att dots ----------------

__global__ __launch_bounds__(256, 3) void k_gemm2(const __half* __restrict__ y1,
                                                  const __half* __restrict__ W2t,
                                                  const float* __restrict__ att_src,
                                                  const float* __restrict__ att_dst,
                                                  __half* __restrict__ h2,
                                                  float* __restrict__ a_s,
                                                  float* __restrict__ a_d, int M) {
    __shared__ __align__(16) __half Ys[64 * 256];    // 32KB, swizzled
    __shared__ __align__(16) __half Ws[32 * 256];    // 16KB, swizzled, permuted slots
    const int tid = threadIdx.x;
    const int row0 = blockIdx.x * 64;

    for (int t = 0; t < 8; ++t) {
        int c = tid + t * 256;            // 0..2047
        int row = c >> 5, ch = c & 31;
        int r = row0 + row;
        float4 v = make_float4(0.f, 0.f, 0.f, 0.f);
        if (r < M) v = *(const float4*)&y1[(size_t)r * 256 + ch * 8];
        *(float4*)((char*)Ys + row * 512 + ((ch * 16) ^ ((row & 7) << 4))) = v;
    }
    for (int t = 0; t < 4; ++t) {
        int c = tid + t * 256;            // 0..1023
        int n = c >> 5, ch = c & 31;
        int p = ((n & 1) << 4) | (n >> 1);     // permuted slot: lane col_l holds cols col_l*2+nt
        float4 v = *(const float4*)&W2t[(size_t)n * 256 + ch * 8];
        *(float4*)((char*)Ws + p * 512 + ((ch * 16) ^ ((p & 7) << 4))) = v;
    }
    __syncthreads();

    const int w = tid >> 6, lane = tid & 63;
    const int col_l = lane & 15, kgrp = lane >> 4;
    const int arow = w * 16 + col_l;
    const int sw = (col_l & 7) << 4;

    f32x4 acc[2];
    acc[0] = (f32x4){0.f, 0.f, 0.f, 0.f};
    acc[1] = (f32x4){0.f, 0.f, 0.f, 0.f};

#pragma unroll
    for (int ks = 0; ks < 8; ++ks) {
        int kchunk = (ks * 4 + kgrp) * 16;
        half8 av = *(const half8*)((const char*)Ys + arow * 512 + (kchunk ^ sw));
#pragma unroll
        for (int nt = 0; nt < 2; ++nt) {
            half8 bv = *(const half8*)((const char*)Ws + (nt * 16 + col_l) * 512 + (kchunk ^ sw));
            acc[nt] = __builtin_amdgcn_mfma_f32_16x16x32_f16(av, bv, acc[nt], 0, 0, 0);
        }
    }

    // lane's acc[nt][reg] = C[row][col = col_l*2 + nt]
    float asv[2], adv[2];
    asv[0] = att_src[col_l * 2]; asv[1] = att_src[col_l * 2 + 1];
    adv[0] = att_dst[col_l * 2]; adv[1] = att_dst[col_l * 2 + 1];
    const int rbase = row0 + w * 16 + kgrp * 4;
#pragma unroll
    for (int reg = 0; reg < 4; ++reg) {
        int gr = rbase + reg;
        if (gr < M) {
            __half2 hv = __floats2half2_rn(acc[0][reg], acc[1][reg]);
            *(__half2*)&h2[(size_t)gr * 32 + col_l * 2] = hv;
        }
        float s_ = fmaf(acc[0][reg], asv[0], acc[1][reg] * asv[1]);
        float d_ = fmaf(acc[0][reg], adv[0], acc[1][reg] * adv[1]);
#pragma unroll
        for (int off = 1; off < 16; off <<= 1) {
            s_ += __shfl_xor(s_, off);
            d_ += __shfl_xor(d_, off);
        }
        if (col_l == 0 && gr < M) { a_s[gr] = s_; a_d[gr] = d_; }
    }
}

// ---------------- agg layer 2 (fused softmax): wave-per-node ----------------

__global__ __launch_bounds__(256) void k_agg2(const __half* __restrict__ h2,
                                              const int* __restrict__ row_ptr,
                                              const int* __restrict__ esrc,
                                              const float* __restrict__ asrc,
                                              const float* __restrict__ adst,
                                              const float* __restrict__ b2,
                                              float* __restrict__ out, int N) {
    __shared__ int ss[4][64];
    __shared__ float sa[4][64];
    int tid = threadIdx.x;
    int wv = tid >> 6, lane = tid & 63;
    int n = blockIdx.x * 4 + wv;
    if (n >= N) return;
    int grp = lane >> 4, cl = lane & 15;
    int e0 = row_ptr[n], e1 = row_ptr[n + 1];
    int deg = e1 - e0;
    float ad = adst[n];
    float2 acc = make_float2(0.f, 0.f);
    float asum = 0.f;

    auto gather = [&](int cnt) {
        int i = 0;
        for (; i + 7 < cnt; i += 8) {
            int ea = i + grp, eb = i + 4 + grp;
            int s0 = ss[wv][ea], s1 = ss[wv][eb];
            float a0 = sa[wv][ea], a1 = sa[wv][eb];
            __half2 v0 = *(const __half2*)&h2[(size_t)s0 * 32 + cl * 2];
            __half2 v1 = *(const __half2*)&h2[(size_t)s1 * 32 + cl * 2];
            float2 f0 = __half22float2(v0), f1 = __half22float2(v1);
            acc.x = fmaf(a0, f0.x, acc.x); acc.y = fmaf(a0, f0.y, acc.y);
            acc.x = fmaf(a1, f1.x, acc.x); acc.y = fmaf(a1, f1.y, acc.y);
        }
        for (; i < cnt; i += 4) {
            int e = i + grp;
            if (e < cnt) {
                int s0 = ss[wv][e];
                float a0 = sa[wv][e];
                __half2 v0 = *(const __half2*)&h2[(size_t)s0 * 32 + cl * 2];
                float2 f0 = __half22float2(v0);
                acc.x = fmaf(a0, f0.x, acc.x); acc.y = fmaf(a0, f0.y, acc.y);
            }
        }
    };

    if (deg <= 64) {
        float l = -3e38f;
        if (lane < deg) {
            int s = esrc[e0 + lane];
            ss[wv][lane] = s;
            l = lrelu(asrc[s] + ad);
        }
        float m = l;
#pragma unroll
        for (int off = 1; off < 64; off <<= 1) m = fmaxf(m, __shfl_xor(m, off));
        float a = 0.f;
        if (lane < deg) {
            a = __expf(l - m);
            sa[wv][lane] = a;
        }
        asum = a;
        gather(deg);
    } else {
        float m = -3e38f;
        for (int p0 = e0; p0 < e1; p0 += 64) {
            int e = p0 + lane;
            if (e < e1) m = fmaxf(m, lrelu(asrc[esrc[e]] + ad));
        }
#pragma unroll
        for (int off = 1; off < 64; off <<= 1) m = fmaxf(m, __shfl_xor(m, off));
        for (int p0 = e0; p0 < e1; p0 += 64) {
            int cnt = min(64, e1 - p0);
            if (lane < cnt) {
                int s = esrc[p0 + lane];
                ss[wv][lane] = s;
                float a = __expf(lrelu(asrc[s] + ad) - m);
                sa[wv][lane] = a;
                asum += a;
            }
            gather(cnt);
        }
    }

    acc.x += __shfl_xor(acc.x, 16); acc.y += __shfl_xor(acc.y, 16);
    acc.x += __shfl_xor(acc.x, 32); acc.y += __shfl_xor(acc.y, 32);
#pragma unroll
    for (int off = 1; off < 64; off <<= 1) asum += __shfl_xor(asum, off);
    if (grp == 0) {
        float inv = 1.f / (asum + 1e-16f);
        float2 o;
        o.x = acc.x * inv + b2[cl * 2];
        o.y = acc.y * inv + b2[cl * 2 + 1];
        *(float2*)&out[(size_t)n * 32 + cl * 2] = o;
    }
}

// ---------------- launcher ----------------

extern "C" void kernel_launch(void* const* d_in, const int* in_sizes, int n_in,
                              void* d_out, int out_size, void* d_ws, size_t ws_size,
                              hipStream_t stream) {
    const float* x   = (const float*)d_in[0];
    const int*   ei  = (const int*)d_in[1];
    const float* W1  = (const float*)d_in[2];
    const float* as1 = (const float*)d_in[3];
    const float* ad1 = (const float*)d_in[4];
    const float* b1  = (const float*)d_in[5];
    const float* W2  = (const float*)d_in[6];
    const float* as2 = (const float*)d_in[7];
    const float* ad2 = (const float*)d_in[8];
    const float* b2  = (const float*)d_in[9];
    float* out = (float*)d_out;

    const int N = in_sizes[0] / 128;   // 50000
    const int E = in_sizes[1] / 2;     // 800000
    const int* src = ei;
    const int* dstp = ei + E;
    const int nb = (N + 1023) / 1024;

    char* ws = (char*)d_ws;
    size_t off = 0;
    auto alloc = [&](size_t nbytes) {
        void* p = ws + off;
        off += (nbytes + 255) & ~(size_t)255;
        return p;
    };
    int* counts    = (int*)alloc((size_t)N * 4);
    int* row_ptr   = (int*)alloc((size_t)(N + 1) * 4);
    int* row_fill  = (int*)alloc((size_t)N * 4);
    int* esrc      = (int*)alloc((size_t)E * 4);
    __half* h1     = (__half*)alloc((size_t)N * 256 * 2);
    __half* y1     = (__half*)alloc((size_t)N * 256 * 2);
    __half* h2     = (__half*)alloc((size_t)N * 32 * 2);
    float* a_s1    = (float*)alloc((size_t)N * 4 * 4);
    float* a_d1    = (float*)alloc((size_t)N * 4 * 4);
    float* a_s2    = (float*)alloc((size_t)N * 4);
    float* a_d2    = (float*)alloc((size_t)N * 4);
    int* bsum      = (int*)alloc((size_t)nb * 4);
    int* boff      = (int*)alloc((size_t)nb * 4);
    __half* Wt     = (__half*)alloc((size_t)256 * 128 * 2);
    __half* W2t    = (__half*)alloc((size_t)32 * 256 * 2);

    hipMemsetAsync(counts, 0, (size_t)N * 4, stream);
    k_hist<<<(E + 255) / 256, 256, 0, stream>>>(dstp, counts, E);
    k_scan1<<<nb, 256, 0, stream>>>(counts, bsum, N);
    k_scan2<<<1, 64, 0, stream>>>(bsum, boff, &row_ptr[N], nb);
    k_scan3<<<nb, 256, 0, stream>>>(counts, boff, row_ptr, row_fill, N);
    k_scatter<<<(E + 255) / 256, 256, 0, stream>>>(src, dstp, row_fill, esrc, E);

    k_wt<<<288, 256, 0, stream>>>(W1, W2, Wt, W2t);

    k_gemm1<<<dim3((N + 127) / 128, 2), 256, 0, stream>>>(x, Wt, as1, ad1, h1, a_s1, a_d1, N);
    k_agg1<<<(N + 3) / 4, 256, 0, stream>>>(h1, row_ptr, esrc, a_s1, a_d1, b1, y1, N);

    k_gemm2<<<(N + 63) / 64, 256, 0, stream>>>(y1, W2t, as2, ad2, h2, a_s2, a_d2, N);
    k_agg2<<<(N + 3) / 4, 256, 0, stream>>>(h2, row_ptr, esrc, a_s2, a_d2, b2, out, N);
}